// Round 1
// baseline (1135.507 us; speedup 1.0000x reference)
//
#include <hip/hip_runtime.h>
#include <cfloat>

#define BROWS 16384

// ---------- wave helpers ----------
__device__ __forceinline__ float wsum64(float v) {
#pragma unroll
  for (int off = 32; off; off >>= 1) v += __shfl_xor(v, off);
  return v;
}
__device__ __forceinline__ float wmax64(float v) {
#pragma unroll
  for (int off = 32; off; off >>= 1) v = fmaxf(v, __shfl_xor(v, off));
  return v;
}
__device__ __forceinline__ float gsum16(float v) {
#pragma unroll
  for (int off = 1; off < 16; off <<= 1) v += __shfl_xor(v, off);
  return v;
}

// ---------- 1) market encoder + router + noise-scale ----------
// grid: 1024 blocks x 256 threads; each wave handles 4 rows.
__global__ __launch_bounds__(256) void encoder_kernel(
    const float* __restrict__ x,
    const float* __restrict__ vol_w, const float* __restrict__ vol_b,
    const float* __restrict__ vol_g, const float* __restrict__ vol_bb,
    const float* __restrict__ trend_w, const float* __restrict__ trend_b,
    const float* __restrict__ trend_g, const float* __restrict__ trend_bb,
    const float* __restrict__ mom_w, const float* __restrict__ mom_b,
    const float* __restrict__ mom_g, const float* __restrict__ mom_bb,
    const float* __restrict__ reg_w, const float* __restrict__ reg_b,
    const float* __restrict__ reg_g, const float* __restrict__ reg_bb,
    const float* __restrict__ rc1_w, const float* __restrict__ rc1_b,
    const float* __restrict__ rc2_w, const float* __restrict__ rc2_b,
    const float* __restrict__ ns1_w, const float* __restrict__ ns1_b,
    const float* __restrict__ ns2_w, const float* __restrict__ ns2_b,
    float* __restrict__ mfrp, float* __restrict__ nsc) {
  const int t = threadIdx.x;
  const int w = t >> 6;
  const int e = t & 63;
  const int br = e >> 4;
  const int rowbase = blockIdx.x * 16 + w * 4;
  const int rb = __builtin_amdgcn_readfirstlane(rowbase);

  const float* wsel = (br == 0) ? vol_w : (br == 1) ? trend_w : (br == 2) ? mom_w : reg_w;
  const float* bsel = (br == 0) ? vol_b : (br == 1) ? trend_b : (br == 2) ? mom_b : reg_b;
  const float* gsel = (br == 0) ? vol_g : (br == 1) ? trend_g : (br == 2) ? mom_g : reg_g;
  const float* bbsel = (br == 0) ? vol_bb : (br == 1) ? trend_bb : (br == 2) ? mom_bb : reg_bb;
  const float* wrow = wsel + (size_t)(e & 15) * 512;

  float acc0 = 0.f, acc1 = 0.f, acc2 = 0.f, acc3 = 0.f;
  const float* xr = x + (size_t)rb * 512;
  for (int k = 0; k < 512; k += 4) {
    const float4 wv = *(const float4*)(wrow + k);
    const float4 x0 = *(const float4*)(xr + k);
    const float4 x1 = *(const float4*)(xr + 512 + k);
    const float4 x2 = *(const float4*)(xr + 1024 + k);
    const float4 x3 = *(const float4*)(xr + 1536 + k);
    acc0 += wv.x * x0.x + wv.y * x0.y + wv.z * x0.z + wv.w * x0.w;
    acc1 += wv.x * x1.x + wv.y * x1.y + wv.z * x1.z + wv.w * x1.w;
    acc2 += wv.x * x2.x + wv.y * x2.y + wv.z * x2.z + wv.w * x2.w;
    acc3 += wv.x * x3.x + wv.y * x3.y + wv.z * x3.z + wv.w * x3.w;
  }
  const float bias = bsel[e & 15];
  const float gv = gsel[e & 15];
  const float bbv = bbsel[e & 15];

  __shared__ float smf[4][4][64];
  __shared__ float shid[4][4][32];
  __shared__ float srp[4][4][4];

  float vr[4] = {acc0 + bias, acc1 + bias, acc2 + bias, acc3 + bias};
#pragma unroll
  for (int r = 0; r < 4; ++r) {
    const float v = fmaxf(vr[r], 0.f);
    const float mu = gsum16(v) * (1.f / 16.f);
    const float d = v - mu;
    const float var = gsum16(d * d) * (1.f / 16.f);
    const float mfv = d * (1.f / sqrtf(var + 1e-5f)) * gv + bbv;
    mfrp[(size_t)(rowbase + r) * 68 + e] = mfv;
    smf[w][r][e] = mfv;
  }
  __syncthreads();
  if (e < 32) {
#pragma unroll
    for (int r = 0; r < 4; ++r) {
      float h = rc1_b[e];
#pragma unroll 8
      for (int j = 0; j < 64; ++j) h += rc1_w[e * 64 + j] * smf[w][r][j];
      shid[w][r][e] = fmaxf(h, 0.f);
    }
  }
  __syncthreads();
  if (e < 16) {
    const int r = e >> 2, l = e & 3;
    float z = rc2_b[l];
#pragma unroll 8
    for (int j = 0; j < 32; ++j) z += rc2_w[l * 32 + j] * shid[w][r][j];
    float mx = z;
    mx = fmaxf(mx, __shfl_xor(mx, 1));
    mx = fmaxf(mx, __shfl_xor(mx, 2));
    const float ex = expf(z - mx);
    float s = ex;
    s += __shfl_xor(s, 1);
    s += __shfl_xor(s, 2);
    const float rp = ex / s;
    srp[w][r][l] = rp;
    mfrp[(size_t)(rowbase + r) * 68 + 64 + l] = rp;
  }
  __syncthreads();
  if (e < 4) {
    const int r = e;
    const float rp0 = srp[w][r][0], rp1 = srp[w][r][1], rp2 = srp[w][r][2], rp3 = srp[w][r][3];
    float z = ns2_b[0];
#pragma unroll
    for (int i = 0; i < 16; ++i) {
      float h = ns1_b[i] + ns1_w[i * 4 + 0] * rp0 + ns1_w[i * 4 + 1] * rp1 +
                ns1_w[i * 4 + 2] * rp2 + ns1_w[i * 4 + 3] * rp3;
      z += ns2_w[i] * fmaxf(h, 0.f);
    }
    nsc[rowbase + r] = 1.f / (1.f + expf(-z));
  }
}

// ---------- 2) fp32 tiled GEMM: C[M,N] = A[M,K] * W[N,K]^T + bias ----------
// GATHER: A row = [x(512) | mfrp(68)]  (gi for the first gating layer)
template <bool GATHER>
__global__ __launch_bounds__(256) void gemm_kernel(
    const float* __restrict__ A, const float* __restrict__ mfrp,
    const float* __restrict__ W, const float* __restrict__ bias,
    float* __restrict__ C, int M, int N, int K) {
  __shared__ float As[16][68];
  __shared__ float Bs[16][68];
  const int t = threadIdx.x;
  const int m0 = blockIdx.x * 64;
  const int n0 = blockIdx.y * 64;
  const int tx = t & 15, ty = t >> 4;
  const int lm = t >> 2;
  const int lk = (t & 3) * 4;
  float acc[4][4] = {};
  const int nk = (K + 15) >> 4;
  for (int kt = 0; kt < nk; ++kt) {
    const int k0 = kt * 16;
    float av[4], wv[4];
#pragma unroll
    for (int j = 0; j < 4; ++j) {
      const int k = k0 + lk + j;
      float va = 0.f;
      if (GATHER) {
        if (k < 512) va = A[(size_t)(m0 + lm) * 512 + k];
        else if (k < 580) va = mfrp[(size_t)(m0 + lm) * 68 + (k - 512)];
      } else {
        if (k < K) va = A[(size_t)(m0 + lm) * K + k];
      }
      av[j] = va;
      const int n = n0 + lm;
      wv[j] = (k < K && n < N) ? W[(size_t)n * K + k] : 0.f;
    }
    __syncthreads();
#pragma unroll
    for (int j = 0; j < 4; ++j) {
      As[lk + j][lm] = av[j];
      Bs[lk + j][lm] = wv[j];
    }
    __syncthreads();
#pragma unroll
    for (int k = 0; k < 16; ++k) {
      const float4 a = *(const float4*)&As[k][ty << 2];
      const float4 b = *(const float4*)&Bs[k][tx << 2];
      const float aa[4] = {a.x, a.y, a.z, a.w};
      const float bb[4] = {b.x, b.y, b.z, b.w};
#pragma unroll
      for (int i = 0; i < 4; ++i)
#pragma unroll
        for (int j = 0; j < 4; ++j) acc[i][j] = fmaf(aa[i], bb[j], acc[i][j]);
    }
  }
#pragma unroll
  for (int i = 0; i < 4; ++i) {
    const int m = m0 + (ty << 2) + i;
#pragma unroll
    for (int j = 0; j < 4; ++j) {
      const int n = n0 + (tx << 2) + j;
      if (n < N) C[(size_t)m * N + n] = acc[i][j] + bias[n];
    }
  }
}

// ---------- 3) in-place row LayerNorm + exact GELU ----------
__global__ __launch_bounds__(256) void ln_gelu_kernel(
    float* __restrict__ Z, const float* __restrict__ gamma,
    const float* __restrict__ beta, const int N) {
  __shared__ float sred[4];
  const int t = threadIdx.x;
  float* zr = Z + (size_t)blockIdx.x * N;
  float vals[5];
  float s = 0.f;
#pragma unroll
  for (int c = 0; c < 5; ++c) {
    const int i = t + c * 256;
    const float v = (i < N) ? zr[i] : 0.f;
    vals[c] = v;
    s += v;
  }
  s = wsum64(s);
  if ((t & 63) == 0) sred[t >> 6] = s;
  __syncthreads();
  const float mu = (sred[0] + sred[1] + sred[2] + sred[3]) / (float)N;
  __syncthreads();
  float q = 0.f;
#pragma unroll
  for (int c = 0; c < 5; ++c) {
    const int i = t + c * 256;
    if (i < N) {
      const float d = vals[c] - mu;
      q += d * d;
    }
  }
  q = wsum64(q);
  if ((t & 63) == 0) sred[t >> 6] = q;
  __syncthreads();
  const float var = (sred[0] + sred[1] + sred[2] + sred[3]) / (float)N;
  const float rstd = 1.f / sqrtf(var + 1e-5f);
#pragma unroll
  for (int c = 0; c < 5; ++c) {
    const int i = t + c * 256;
    if (i < N) {
      const float y = (vals[c] - mu) * rstd * gamma[i] + beta[i];
      zr[i] = 0.5f * y * (1.f + erff(y * 0.70710678118654752f));
    }
  }
}

// ---------- 4) final: +rp*spec^T, noise, top-2, gates, partials ----------
// grid: 256 blocks x 256 threads; wave = one row per iteration, 16 iters.
__global__ __launch_bounds__(256) void final_kernel(
    const float* __restrict__ clean, const float* __restrict__ mfrp,
    const float* __restrict__ nsc, const float* __restrict__ noise,
    const float* __restrict__ spec, float* __restrict__ out,
    float* __restrict__ pg, float* __restrict__ pl) {
  const int t = threadIdx.x;
  const int w = t >> 6;
  const int e = t & 63;
  __shared__ float sg[4][64];
  __shared__ float sl[4][64];
  const float4 sp = *(const float4*)(spec + e * 4);
  float accg = 0.f, accl = 0.f;
  for (int it = 0; it < 16; ++it) {
    const int row = blockIdx.x * 64 + it * 4 + w;
    const float4 rp = *(const float4*)(mfrp + (size_t)row * 68 + 64);
    float c = clean[(size_t)row * 64 + e];
    c += rp.x * sp.x + rp.y * sp.y + rp.z * sp.z + rp.w * sp.w;
    const float nv = noise[(size_t)row * 64 + e];
    const float noisy = c + nv * nsc[row];
    // top-1
    float v = noisy;
    int ix = e;
#pragma unroll
    for (int off = 32; off; off >>= 1) {
      const float ov = __shfl_xor(v, off);
      const int oi = __shfl_xor(ix, off);
      if (ov > v || (ov == v && oi < ix)) { v = ov; ix = oi; }
    }
    const float v1 = v;
    const int i1 = ix;
    // top-2
    float v2 = (e == i1) ? -FLT_MAX : noisy;
    int ix2 = e;
#pragma unroll
    for (int off = 32; off; off >>= 1) {
      const float ov = __shfl_xor(v2, off);
      const int oi = __shfl_xor(ix2, off);
      if (ov > v2 || (ov == v2 && oi < ix2)) { v2 = ov; ix2 = oi; }
    }
    const int i2 = ix2;
    if (e == 0) {
      const float texp = expf(v2 - v1);
      const float tw0 = 1.f / (1.f + texp);
      out[(size_t)row * 2 + 0] = tw0;
      out[(size_t)row * 2 + 1] = texp * tw0;
      out[32768 + (size_t)row * 2 + 0] = (float)i1;
      out[32768 + (size_t)row * 2 + 1] = (float)i2;
    }
    // gates = softmax(clean)
    const float mx = wmax64(c);
    const float p = expf(c - mx);
    const float ssum = wsum64(p);
    accg += p / ssum;
    accl += (e == i1 || e == i2) ? 1.f : 0.f;
  }
  sg[w][e] = accg;
  sl[w][e] = accl;
  __syncthreads();
  if (t < 64) {
    pg[blockIdx.x * 64 + t] = sg[0][t] + sg[1][t] + sg[2][t] + sg[3][t];
    pl[blockIdx.x * 64 + t] = sl[0][t] + sl[1][t] + sl[2][t] + sl[3][t];
  }
}

// ---------- 5) aux loss ----------
__global__ void loss_kernel(const float* __restrict__ pg,
                            const float* __restrict__ pl,
                            float* __restrict__ out) {
  const int e = threadIdx.x;  // 64 threads
  float g = 0.f, l = 0.f;
  for (int b = 0; b < 256; ++b) {
    g += pg[b * 64 + e];
    l += pl[b * 64 + e];
  }
  const float prob = g * (1.f / 16384.f);
  const float ld = l * (1.f / 16384.f);
  const float load_loss = 64.f * wsum64(prob * ld);
  const float sgs = wsum64(g);
  const float mean = sgs * (1.f / 64.f);
  const float d = g - mean;
  const float var = wsum64(d * d) * (1.f / 63.f);
  if (e == 0) out[65536] = 0.01f * load_loss + 0.01f * (var / mean);
}

extern "C" void kernel_launch(void* const* d_in, const int* in_sizes, int n_in,
                              void* d_out, int out_size, void* d_ws, size_t ws_size,
                              hipStream_t stream) {
  (void)in_sizes; (void)n_in; (void)out_size; (void)ws_size;
  const float* x = (const float*)d_in[0];
  const float* noise = (const float*)d_in[1];
  const float* vol_w = (const float*)d_in[2];
  const float* vol_b = (const float*)d_in[3];
  const float* vol_g = (const float*)d_in[4];
  const float* vol_bb = (const float*)d_in[5];
  const float* trend_w = (const float*)d_in[6];
  const float* trend_b = (const float*)d_in[7];
  const float* trend_g = (const float*)d_in[8];
  const float* trend_bb = (const float*)d_in[9];
  const float* mom_w = (const float*)d_in[10];
  const float* mom_b = (const float*)d_in[11];
  const float* mom_g = (const float*)d_in[12];
  const float* mom_bb = (const float*)d_in[13];
  const float* reg_w = (const float*)d_in[14];
  const float* reg_b = (const float*)d_in[15];
  const float* reg_g = (const float*)d_in[16];
  const float* reg_bb = (const float*)d_in[17];
  const float* rc1_w = (const float*)d_in[18];
  const float* rc1_b = (const float*)d_in[19];
  const float* rc2_w = (const float*)d_in[20];
  const float* rc2_b = (const float*)d_in[21];
  const float* g1_w = (const float*)d_in[22];
  const float* g1_b = (const float*)d_in[23];
  const float* g1_g = (const float*)d_in[24];
  const float* g1_bb = (const float*)d_in[25];
  const float* g2_w = (const float*)d_in[26];
  const float* g2_b = (const float*)d_in[27];
  const float* g2_g = (const float*)d_in[28];
  const float* g2_bb = (const float*)d_in[29];
  const float* g3_w = (const float*)d_in[30];
  const float* g3_b = (const float*)d_in[31];
  const float* ns1_w = (const float*)d_in[32];
  const float* ns1_b = (const float*)d_in[33];
  const float* ns2_w = (const float*)d_in[34];
  const float* ns2_b = (const float*)d_in[35];
  const float* spec = (const float*)d_in[36];
  float* out = (float*)d_out;

  const int B = BROWS;
  float* ws = (float*)d_ws;
  float* mfrp = ws;                   // B*68
  float* nsc = mfrp + (size_t)B * 68; // B
  float* z1 = nsc + B;                // B*1160
  float* z2 = z1 + (size_t)B * 1160;  // B*580
  float* cln = z2 + (size_t)B * 580;  // B*64
  float* pg = cln + (size_t)B * 64;   // 256*64
  float* pl = pg + 256 * 64;          // 256*64

  encoder_kernel<<<1024, 256, 0, stream>>>(
      x, vol_w, vol_b, vol_g, vol_bb, trend_w, trend_b, trend_g, trend_bb,
      mom_w, mom_b, mom_g, mom_bb, reg_w, reg_b, reg_g, reg_bb,
      rc1_w, rc1_b, rc2_w, rc2_b, ns1_w, ns1_b, ns2_w, ns2_b, mfrp, nsc);

  gemm_kernel<true><<<dim3(256, 19), 256, 0, stream>>>(
      x, mfrp, g1_w, g1_b, z1, B, 1160, 580);
  ln_gelu_kernel<<<B, 256, 0, stream>>>(z1, g1_g, g1_bb, 1160);

  gemm_kernel<false><<<dim3(256, 10), 256, 0, stream>>>(
      z1, nullptr, g2_w, g2_b, z2, B, 580, 1160);
  ln_gelu_kernel<<<B, 256, 0, stream>>>(z2, g2_g, g2_bb, 580);

  gemm_kernel<false><<<dim3(256, 1), 256, 0, stream>>>(
      z2, nullptr, g3_w, g3_b, cln, B, 64, 580);

  final_kernel<<<256, 256, 0, stream>>>(cln, mfrp, nsc, noise, spec, out, pg, pl);
  loss_kernel<<<1, 64, 0, stream>>>(pg, pl, out);
}

// Round 2
// 911.284 us; speedup vs baseline: 1.2461x; 1.2461x over previous
//
#include <hip/hip_runtime.h>
#include <cfloat>

#define BROWS 16384

// ---------- wave helpers ----------
__device__ __forceinline__ float wsum64(float v) {
#pragma unroll
  for (int off = 32; off; off >>= 1) v += __shfl_xor(v, off);
  return v;
}
__device__ __forceinline__ float wmax64(float v) {
#pragma unroll
  for (int off = 32; off; off >>= 1) v = fmaxf(v, __shfl_xor(v, off));
  return v;
}
__device__ __forceinline__ float gsum16(float v) {
#pragma unroll
  for (int off = 1; off < 16; off <<= 1) v += __shfl_xor(v, off);
  return v;
}

// ---------- 1) market encoder + router + noise-scale ----------
// grid: 1024 blocks x 256 threads; each wave handles 4 rows.
__global__ __launch_bounds__(256) void encoder_kernel(
    const float* __restrict__ x,
    const float* __restrict__ vol_w, const float* __restrict__ vol_b,
    const float* __restrict__ vol_g, const float* __restrict__ vol_bb,
    const float* __restrict__ trend_w, const float* __restrict__ trend_b,
    const float* __restrict__ trend_g, const float* __restrict__ trend_bb,
    const float* __restrict__ mom_w, const float* __restrict__ mom_b,
    const float* __restrict__ mom_g, const float* __restrict__ mom_bb,
    const float* __restrict__ reg_w, const float* __restrict__ reg_b,
    const float* __restrict__ reg_g, const float* __restrict__ reg_bb,
    const float* __restrict__ rc1_w, const float* __restrict__ rc1_b,
    const float* __restrict__ rc2_w, const float* __restrict__ rc2_b,
    const float* __restrict__ ns1_w, const float* __restrict__ ns1_b,
    const float* __restrict__ ns2_w, const float* __restrict__ ns2_b,
    float* __restrict__ mfrp, float* __restrict__ nsc) {
  const int t = threadIdx.x;
  const int w = t >> 6;
  const int e = t & 63;
  const int br = e >> 4;
  const int rowbase = blockIdx.x * 16 + w * 4;
  const int rb = __builtin_amdgcn_readfirstlane(rowbase);

  const float* wsel = (br == 0) ? vol_w : (br == 1) ? trend_w : (br == 2) ? mom_w : reg_w;
  const float* bsel = (br == 0) ? vol_b : (br == 1) ? trend_b : (br == 2) ? mom_b : reg_b;
  const float* gsel = (br == 0) ? vol_g : (br == 1) ? trend_g : (br == 2) ? mom_g : reg_g;
  const float* bbsel = (br == 0) ? vol_bb : (br == 1) ? trend_bb : (br == 2) ? mom_bb : reg_bb;
  const float* wrow = wsel + (size_t)(e & 15) * 512;

  float acc0 = 0.f, acc1 = 0.f, acc2 = 0.f, acc3 = 0.f;
  const float* xr = x + (size_t)rb * 512;
  for (int k = 0; k < 512; k += 4) {
    const float4 wv = *(const float4*)(wrow + k);
    const float4 x0 = *(const float4*)(xr + k);
    const float4 x1 = *(const float4*)(xr + 512 + k);
    const float4 x2 = *(const float4*)(xr + 1024 + k);
    const float4 x3 = *(const float4*)(xr + 1536 + k);
    acc0 += wv.x * x0.x + wv.y * x0.y + wv.z * x0.z + wv.w * x0.w;
    acc1 += wv.x * x1.x + wv.y * x1.y + wv.z * x1.z + wv.w * x1.w;
    acc2 += wv.x * x2.x + wv.y * x2.y + wv.z * x2.z + wv.w * x2.w;
    acc3 += wv.x * x3.x + wv.y * x3.y + wv.z * x3.z + wv.w * x3.w;
  }
  const float bias = bsel[e & 15];
  const float gv = gsel[e & 15];
  const float bbv = bbsel[e & 15];

  __shared__ float smf[4][4][64];
  __shared__ float shid[4][4][32];
  __shared__ float srp[4][4][4];

  float vr[4] = {acc0 + bias, acc1 + bias, acc2 + bias, acc3 + bias};
#pragma unroll
  for (int r = 0; r < 4; ++r) {
    const float v = fmaxf(vr[r], 0.f);
    const float mu = gsum16(v) * (1.f / 16.f);
    const float d = v - mu;
    const float var = gsum16(d * d) * (1.f / 16.f);
    const float mfv = d * (1.f / sqrtf(var + 1e-5f)) * gv + bbv;
    mfrp[(size_t)(rowbase + r) * 68 + e] = mfv;
    smf[w][r][e] = mfv;
  }
  __syncthreads();
  if (e < 32) {
#pragma unroll
    for (int r = 0; r < 4; ++r) {
      float h = rc1_b[e];
#pragma unroll 8
      for (int j = 0; j < 64; ++j) h += rc1_w[e * 64 + j] * smf[w][r][j];
      shid[w][r][e] = fmaxf(h, 0.f);
    }
  }
  __syncthreads();
  if (e < 16) {
    const int r = e >> 2, l = e & 3;
    float z = rc2_b[l];
#pragma unroll 8
    for (int j = 0; j < 32; ++j) z += rc2_w[l * 32 + j] * shid[w][r][j];
    float mx = z;
    mx = fmaxf(mx, __shfl_xor(mx, 1));
    mx = fmaxf(mx, __shfl_xor(mx, 2));
    const float ex = expf(z - mx);
    float s = ex;
    s += __shfl_xor(s, 1);
    s += __shfl_xor(s, 2);
    const float rp = ex / s;
    srp[w][r][l] = rp;
    mfrp[(size_t)(rowbase + r) * 68 + 64 + l] = rp;
  }
  __syncthreads();
  if (e < 4) {
    const int r = e;
    const float rp0 = srp[w][r][0], rp1 = srp[w][r][1], rp2 = srp[w][r][2], rp3 = srp[w][r][3];
    float z = ns2_b[0];
#pragma unroll
    for (int i = 0; i < 16; ++i) {
      float h = ns1_b[i] + ns1_w[i * 4 + 0] * rp0 + ns1_w[i * 4 + 1] * rp1 +
                ns1_w[i * 4 + 2] * rp2 + ns1_w[i * 4 + 3] * rp3;
      z += ns2_w[i] * fmaxf(h, 0.f);
    }
    nsc[rowbase + r] = 1.f / (1.f + expf(-z));
  }
}

// ---------- 2) fp32 tiled GEMM: C[M,N] = A[M,K] * W[N,K]^T + bias ----------
// Block tile 128x128, BK=16, 256 threads, 8x8 per-thread micro-tile
// (2x2 arrangement of float4 x float4). LDS tiles stored K-major with
// leading dim 132 (pad) -> reads are broadcast / 2-way only (free).
// GATHER: A row = [x(512) | mfrp(68)]  (gi for the first gating layer)
template <bool GATHER>
__global__ __launch_bounds__(256, 4) void gemm128_kernel(
    const float* __restrict__ A, const float* __restrict__ mfrp,
    const float* __restrict__ W, const float* __restrict__ bias,
    float* __restrict__ C, int M, int N, int K) {
  __shared__ float As[16][132];
  __shared__ float Bs[16][132];
  const int t = threadIdx.x;
  const int m0 = blockIdx.x * 128;
  const int n0 = blockIdx.y * 128;
  const int tx = t & 15, ty = t >> 4;
  const int srow = t >> 1;        // 0..127 (tile row for staging)
  const int skc = (t & 1) * 8;    // 0 or 8 (k offset for staging)

  float acc[2][2][4][4] = {};
  const int nk = (K + 15) >> 4;
  const int arow = m0 + srow;
  const int brow = n0 + srow;
  const bool bvalid = brow < N;

  for (int kt = 0; kt < nk; ++kt) {
    const int k0 = kt * 16;
    float4 av[2], bv[2];
#pragma unroll
    for (int c = 0; c < 2; ++c) {
      const int k = k0 + skc + c * 4;
      float4 va = {0.f, 0.f, 0.f, 0.f};
      if (GATHER) {
        if (k < 512) va = *(const float4*)(A + (size_t)arow * 512 + k);
        else if (k < 580) va = *(const float4*)(mfrp + (size_t)arow * 68 + (k - 512));
      } else {
        if (k < K) va = *(const float4*)(A + (size_t)arow * K + k);
      }
      av[c] = va;
      float4 vb = {0.f, 0.f, 0.f, 0.f};
      if (bvalid && k < K) vb = *(const float4*)(W + (size_t)brow * K + k);
      bv[c] = vb;
    }
    __syncthreads();  // previous tile fully consumed
#pragma unroll
    for (int c = 0; c < 2; ++c) {
      As[skc + c * 4 + 0][srow] = av[c].x;
      As[skc + c * 4 + 1][srow] = av[c].y;
      As[skc + c * 4 + 2][srow] = av[c].z;
      As[skc + c * 4 + 3][srow] = av[c].w;
      Bs[skc + c * 4 + 0][srow] = bv[c].x;
      Bs[skc + c * 4 + 1][srow] = bv[c].y;
      Bs[skc + c * 4 + 2][srow] = bv[c].z;
      Bs[skc + c * 4 + 3][srow] = bv[c].w;
    }
    __syncthreads();
#pragma unroll
    for (int k = 0; k < 16; ++k) {
      const float4 a0 = *(const float4*)&As[k][ty << 2];
      const float4 a1 = *(const float4*)&As[k][(ty << 2) + 64];
      const float4 b0 = *(const float4*)&Bs[k][tx << 2];
      const float4 b1 = *(const float4*)&Bs[k][(tx << 2) + 64];
      const float aa[2][4] = {{a0.x, a0.y, a0.z, a0.w}, {a1.x, a1.y, a1.z, a1.w}};
      const float bb[2][4] = {{b0.x, b0.y, b0.z, b0.w}, {b1.x, b1.y, b1.z, b1.w}};
#pragma unroll
      for (int i2 = 0; i2 < 2; ++i2)
#pragma unroll
        for (int i = 0; i < 4; ++i)
#pragma unroll
          for (int j2 = 0; j2 < 2; ++j2)
#pragma unroll
            for (int j = 0; j < 4; ++j)
              acc[i2][j2][i][j] = fmaf(aa[i2][i], bb[j2][j], acc[i2][j2][i][j]);
    }
  }
  // epilogue: C = acc + bias (float4 stores; all col segments 4-aligned)
#pragma unroll
  for (int j2 = 0; j2 < 2; ++j2) {
    const int n = n0 + j2 * 64 + (tx << 2);
    if (n < N) {
      const float4 bz = *(const float4*)(bias + n);
#pragma unroll
      for (int i2 = 0; i2 < 2; ++i2)
#pragma unroll
        for (int i = 0; i < 4; ++i) {
          const int m = m0 + i2 * 64 + (ty << 2) + i;
          float4 o;
          o.x = acc[i2][j2][i][0] + bz.x;
          o.y = acc[i2][j2][i][1] + bz.y;
          o.z = acc[i2][j2][i][2] + bz.z;
          o.w = acc[i2][j2][i][3] + bz.w;
          *(float4*)(C + (size_t)m * N + n) = o;
        }
    }
  }
}

// ---------- 3) in-place row LayerNorm + exact GELU ----------
__global__ __launch_bounds__(256) void ln_gelu_kernel(
    float* __restrict__ Z, const float* __restrict__ gamma,
    const float* __restrict__ beta, const int N) {
  __shared__ float sred[4];
  const int t = threadIdx.x;
  float* zr = Z + (size_t)blockIdx.x * N;
  float vals[5];
  float s = 0.f;
#pragma unroll
  for (int c = 0; c < 5; ++c) {
    const int i = t + c * 256;
    const float v = (i < N) ? zr[i] : 0.f;
    vals[c] = v;
    s += v;
  }
  s = wsum64(s);
  if ((t & 63) == 0) sred[t >> 6] = s;
  __syncthreads();
  const float mu = (sred[0] + sred[1] + sred[2] + sred[3]) / (float)N;
  __syncthreads();
  float q = 0.f;
#pragma unroll
  for (int c = 0; c < 5; ++c) {
    const int i = t + c * 256;
    if (i < N) {
      const float d = vals[c] - mu;
      q += d * d;
    }
  }
  q = wsum64(q);
  if ((t & 63) == 0) sred[t >> 6] = q;
  __syncthreads();
  const float var = (sred[0] + sred[1] + sred[2] + sred[3]) / (float)N;
  const float rstd = 1.f / sqrtf(var + 1e-5f);
#pragma unroll
  for (int c = 0; c < 5; ++c) {
    const int i = t + c * 256;
    if (i < N) {
      const float y = (vals[c] - mu) * rstd * gamma[i] + beta[i];
      zr[i] = 0.5f * y * (1.f + erff(y * 0.70710678118654752f));
    }
  }
}

// ---------- 4) final: +rp*spec^T, noise, top-2, gates, partials ----------
// grid: 256 blocks x 256 threads; wave = one row per iteration, 16 iters.
__global__ __launch_bounds__(256) void final_kernel(
    const float* __restrict__ clean, const float* __restrict__ mfrp,
    const float* __restrict__ nsc, const float* __restrict__ noise,
    const float* __restrict__ spec, float* __restrict__ out,
    float* __restrict__ pg, float* __restrict__ pl) {
  const int t = threadIdx.x;
  const int w = t >> 6;
  const int e = t & 63;
  __shared__ float sg[4][64];
  __shared__ float sl[4][64];
  const float4 sp = *(const float4*)(spec + e * 4);
  float accg = 0.f, accl = 0.f;
  for (int it = 0; it < 16; ++it) {
    const int row = blockIdx.x * 64 + it * 4 + w;
    const float4 rp = *(const float4*)(mfrp + (size_t)row * 68 + 64);
    float c = clean[(size_t)row * 64 + e];
    c += rp.x * sp.x + rp.y * sp.y + rp.z * sp.z + rp.w * sp.w;
    const float nv = noise[(size_t)row * 64 + e];
    const float noisy = c + nv * nsc[row];
    // top-1
    float v = noisy;
    int ix = e;
#pragma unroll
    for (int off = 32; off; off >>= 1) {
      const float ov = __shfl_xor(v, off);
      const int oi = __shfl_xor(ix, off);
      if (ov > v || (ov == v && oi < ix)) { v = ov; ix = oi; }
    }
    const float v1 = v;
    const int i1 = ix;
    // top-2
    float v2 = (e == i1) ? -FLT_MAX : noisy;
    int ix2 = e;
#pragma unroll
    for (int off = 32; off; off >>= 1) {
      const float ov = __shfl_xor(v2, off);
      const int oi = __shfl_xor(ix2, off);
      if (ov > v2 || (ov == v2 && oi < ix2)) { v2 = ov; ix2 = oi; }
    }
    const int i2 = ix2;
    if (e == 0) {
      const float texp = expf(v2 - v1);
      const float tw0 = 1.f / (1.f + texp);
      out[(size_t)row * 2 + 0] = tw0;
      out[(size_t)row * 2 + 1] = texp * tw0;
      out[32768 + (size_t)row * 2 + 0] = (float)i1;
      out[32768 + (size_t)row * 2 + 1] = (float)i2;
    }
    // gates = softmax(clean)
    const float mx = wmax64(c);
    const float p = expf(c - mx);
    const float ssum = wsum64(p);
    accg += p / ssum;
    accl += (e == i1 || e == i2) ? 1.f : 0.f;
  }
  sg[w][e] = accg;
  sl[w][e] = accl;
  __syncthreads();
  if (t < 64) {
    pg[blockIdx.x * 64 + t] = sg[0][t] + sg[1][t] + sg[2][t] + sg[3][t];
    pl[blockIdx.x * 64 + t] = sl[0][t] + sl[1][t] + sl[2][t] + sl[3][t];
  }
}

// ---------- 5) aux loss ----------
__global__ void loss_kernel(const float* __restrict__ pg,
                            const float* __restrict__ pl,
                            float* __restrict__ out) {
  const int e = threadIdx.x;  // 64 threads
  float g = 0.f, l = 0.f;
  for (int b = 0; b < 256; ++b) {
    g += pg[b * 64 + e];
    l += pl[b * 64 + e];
  }
  const float prob = g * (1.f / 16384.f);
  const float ld = l * (1.f / 16384.f);
  const float load_loss = 64.f * wsum64(prob * ld);
  const float sgs = wsum64(g);
  const float mean = sgs * (1.f / 64.f);
  const float d = g - mean;
  const float var = wsum64(d * d) * (1.f / 63.f);
  if (e == 0) out[65536] = 0.01f * load_loss + 0.01f * (var / mean);
}

extern "C" void kernel_launch(void* const* d_in, const int* in_sizes, int n_in,
                              void* d_out, int out_size, void* d_ws, size_t ws_size,
                              hipStream_t stream) {
  (void)in_sizes; (void)n_in; (void)out_size; (void)ws_size;
  const float* x = (const float*)d_in[0];
  const float* noise = (const float*)d_in[1];
  const float* vol_w = (const float*)d_in[2];
  const float* vol_b = (const float*)d_in[3];
  const float* vol_g = (const float*)d_in[4];
  const float* vol_bb = (const float*)d_in[5];
  const float* trend_w = (const float*)d_in[6];
  const float* trend_b = (const float*)d_in[7];
  const float* trend_g = (const float*)d_in[8];
  const float* trend_bb = (const float*)d_in[9];
  const float* mom_w = (const float*)d_in[10];
  const float* mom_b = (const float*)d_in[11];
  const float* mom_g = (const float*)d_in[12];
  const float* mom_bb = (const float*)d_in[13];
  const float* reg_w = (const float*)d_in[14];
  const float* reg_b = (const float*)d_in[15];
  const float* reg_g = (const float*)d_in[16];
  const float* reg_bb = (const float*)d_in[17];
  const float* rc1_w = (const float*)d_in[18];
  const float* rc1_b = (const float*)d_in[19];
  const float* rc2_w = (const float*)d_in[20];
  const float* rc2_b = (const float*)d_in[21];
  const float* g1_w = (const float*)d_in[22];
  const float* g1_b = (const float*)d_in[23];
  const float* g1_g = (const float*)d_in[24];
  const float* g1_bb = (const float*)d_in[25];
  const float* g2_w = (const float*)d_in[26];
  const float* g2_b = (const float*)d_in[27];
  const float* g2_g = (const float*)d_in[28];
  const float* g2_bb = (const float*)d_in[29];
  const float* g3_w = (const float*)d_in[30];
  const float* g3_b = (const float*)d_in[31];
  const float* ns1_w = (const float*)d_in[32];
  const float* ns1_b = (const float*)d_in[33];
  const float* ns2_w = (const float*)d_in[34];
  const float* ns2_b = (const float*)d_in[35];
  const float* spec = (const float*)d_in[36];
  float* out = (float*)d_out;

  const int B = BROWS;
  float* ws = (float*)d_ws;
  float* mfrp = ws;                   // B*68
  float* nsc = mfrp + (size_t)B * 68; // B
  float* z1 = nsc + B;                // B*1160
  float* z2 = z1 + (size_t)B * 1160;  // B*580
  float* cln = z2 + (size_t)B * 580;  // B*64
  float* pg = cln + (size_t)B * 64;   // 256*64
  float* pl = pg + 256 * 64;          // 256*64

  encoder_kernel<<<1024, 256, 0, stream>>>(
      x, vol_w, vol_b, vol_g, vol_bb, trend_w, trend_b, trend_g, trend_bb,
      mom_w, mom_b, mom_g, mom_bb, reg_w, reg_b, reg_g, reg_bb,
      rc1_w, rc1_b, rc2_w, rc2_b, ns1_w, ns1_b, ns2_w, ns2_b, mfrp, nsc);

  // G1: [16384,580] x [1160,580]^T -> z1
  gemm128_kernel<true><<<dim3(128, 10), 256, 0, stream>>>(
      x, mfrp, g1_w, g1_b, z1, B, 1160, 580);
  ln_gelu_kernel<<<B, 256, 0, stream>>>(z1, g1_g, g1_bb, 1160);

  // G2: [16384,1160] x [580,1160]^T -> z2
  gemm128_kernel<false><<<dim3(128, 5), 256, 0, stream>>>(
      z1, nullptr, g2_w, g2_b, z2, B, 580, 1160);
  ln_gelu_kernel<<<B, 256, 0, stream>>>(z2, g2_g, g2_bb, 580);

  // G3: [16384,580] x [64,580]^T -> clean
  gemm128_kernel<false><<<dim3(128, 1), 256, 0, stream>>>(
      z2, nullptr, g3_w, g3_b, cln, B, 64, 580);

  final_kernel<<<256, 256, 0, stream>>>(cln, mfrp, nsc, noise, spec, out, pg, pl);
  loss_kernel<<<1, 64, 0, stream>>>(pg, pl, out);
}

// Round 3
// 657.573 us; speedup vs baseline: 1.7268x; 1.3858x over previous
//
#include <hip/hip_runtime.h>
#include <cfloat>

#define BROWS 16384

typedef float f32x4 __attribute__((ext_vector_type(4)));
typedef short s16x8 __attribute__((ext_vector_type(8)));

// ---------- wave helpers ----------
__device__ __forceinline__ float wsum64(float v) {
#pragma unroll
  for (int off = 32; off; off >>= 1) v += __shfl_xor(v, off);
  return v;
}
__device__ __forceinline__ float wmax64(float v) {
#pragma unroll
  for (int off = 32; off; off >>= 1) v = fmaxf(v, __shfl_xor(v, off));
  return v;
}
__device__ __forceinline__ float gsum16(float v) {
#pragma unroll
  for (int off = 1; off < 16; off <<= 1) v += __shfl_xor(v, off);
  return v;
}

// bf16 round-to-nearest-even pack/unpack (bit tricks; values finite)
__device__ __forceinline__ unsigned short f2bf_rne(float f) {
  unsigned int u = __float_as_uint(f);
  return (unsigned short)((u + 0x7FFFu + ((u >> 16) & 1u)) >> 16);
}
__device__ __forceinline__ float bf2f(unsigned short h) {
  return __uint_as_float(((unsigned int)h) << 16);
}

// ---------- 1) market encoder + router + noise-scale ----------
__global__ __launch_bounds__(256) void encoder_kernel(
    const float* __restrict__ x,
    const float* __restrict__ vol_w, const float* __restrict__ vol_b,
    const float* __restrict__ vol_g, const float* __restrict__ vol_bb,
    const float* __restrict__ trend_w, const float* __restrict__ trend_b,
    const float* __restrict__ trend_g, const float* __restrict__ trend_bb,
    const float* __restrict__ mom_w, const float* __restrict__ mom_b,
    const float* __restrict__ mom_g, const float* __restrict__ mom_bb,
    const float* __restrict__ reg_w, const float* __restrict__ reg_b,
    const float* __restrict__ reg_g, const float* __restrict__ reg_bb,
    const float* __restrict__ rc1_w, const float* __restrict__ rc1_b,
    const float* __restrict__ rc2_w, const float* __restrict__ rc2_b,
    const float* __restrict__ ns1_w, const float* __restrict__ ns1_b,
    const float* __restrict__ ns2_w, const float* __restrict__ ns2_b,
    float* __restrict__ mfrp, float* __restrict__ nsc) {
  const int t = threadIdx.x;
  const int w = t >> 6;
  const int e = t & 63;
  const int br = e >> 4;
  const int rowbase = blockIdx.x * 16 + w * 4;
  const int rb = __builtin_amdgcn_readfirstlane(rowbase);

  const float* wsel = (br == 0) ? vol_w : (br == 1) ? trend_w : (br == 2) ? mom_w : reg_w;
  const float* bsel = (br == 0) ? vol_b : (br == 1) ? trend_b : (br == 2) ? mom_b : reg_b;
  const float* gsel = (br == 0) ? vol_g : (br == 1) ? trend_g : (br == 2) ? mom_g : reg_g;
  const float* bbsel = (br == 0) ? vol_bb : (br == 1) ? trend_bb : (br == 2) ? mom_bb : reg_bb;
  const float* wrow = wsel + (size_t)(e & 15) * 512;

  float acc0 = 0.f, acc1 = 0.f, acc2 = 0.f, acc3 = 0.f;
  const float* xr = x + (size_t)rb * 512;
  for (int k = 0; k < 512; k += 4) {
    const float4 wv = *(const float4*)(wrow + k);
    const float4 x0 = *(const float4*)(xr + k);
    const float4 x1 = *(const float4*)(xr + 512 + k);
    const float4 x2 = *(const float4*)(xr + 1024 + k);
    const float4 x3 = *(const float4*)(xr + 1536 + k);
    acc0 += wv.x * x0.x + wv.y * x0.y + wv.z * x0.z + wv.w * x0.w;
    acc1 += wv.x * x1.x + wv.y * x1.y + wv.z * x1.z + wv.w * x1.w;
    acc2 += wv.x * x2.x + wv.y * x2.y + wv.z * x2.z + wv.w * x2.w;
    acc3 += wv.x * x3.x + wv.y * x3.y + wv.z * x3.z + wv.w * x3.w;
  }
  const float bias = bsel[e & 15];
  const float gv = gsel[e & 15];
  const float bbv = bbsel[e & 15];

  __shared__ float smf[4][4][64];
  __shared__ float shid[4][4][32];
  __shared__ float srp[4][4][4];

  float vr[4] = {acc0 + bias, acc1 + bias, acc2 + bias, acc3 + bias};
#pragma unroll
  for (int r = 0; r < 4; ++r) {
    const float v = fmaxf(vr[r], 0.f);
    const float mu = gsum16(v) * (1.f / 16.f);
    const float d = v - mu;
    const float var = gsum16(d * d) * (1.f / 16.f);
    const float mfv = d * (1.f / sqrtf(var + 1e-5f)) * gv + bbv;
    mfrp[(size_t)(rowbase + r) * 68 + e] = mfv;
    smf[w][r][e] = mfv;
  }
  __syncthreads();
  if (e < 32) {
#pragma unroll
    for (int r = 0; r < 4; ++r) {
      float h = rc1_b[e];
#pragma unroll 8
      for (int j = 0; j < 64; ++j) h += rc1_w[e * 64 + j] * smf[w][r][j];
      shid[w][r][e] = fmaxf(h, 0.f);
    }
  }
  __syncthreads();
  if (e < 16) {
    const int r = e >> 2, l = e & 3;
    float z = rc2_b[l];
#pragma unroll 8
    for (int j = 0; j < 32; ++j) z += rc2_w[l * 32 + j] * shid[w][r][j];
    float mx = z;
    mx = fmaxf(mx, __shfl_xor(mx, 1));
    mx = fmaxf(mx, __shfl_xor(mx, 2));
    const float ex = expf(z - mx);
    float s = ex;
    s += __shfl_xor(s, 1);
    s += __shfl_xor(s, 2);
    const float rp = ex / s;
    srp[w][r][l] = rp;
    mfrp[(size_t)(rowbase + r) * 68 + 64 + l] = rp;
  }
  __syncthreads();
  if (e < 4) {
    const int r = e;
    const float rp0 = srp[w][r][0], rp1 = srp[w][r][1], rp2 = srp[w][r][2], rp3 = srp[w][r][3];
    float z = ns2_b[0];
#pragma unroll
    for (int i = 0; i < 16; ++i) {
      float h = ns1_b[i] + ns1_w[i * 4 + 0] * rp0 + ns1_w[i * 4 + 1] * rp1 +
                ns1_w[i * 4 + 2] * rp2 + ns1_w[i * 4 + 3] * rp3;
      z += ns2_w[i] * fmaxf(h, 0.f);
    }
    nsc[rowbase + r] = 1.f / (1.f + expf(-z));
  }
}

// ---------- 2) split-bf16x6 MFMA GEMM: C[M,N] = A[M,K]*W[N,K]^T + bias ----------
// 3-limb bf16 decomposition (err <= 2^-27 rel) -> 6 MFMA products -> fp32-level
// accuracy at the bf16 matrix-core rate (ceiling 2075/6 ~= 346 TF).
// Tile 128x128, BK=32, 4 waves (2x2 of 64x64), 16x16x32 bf16 MFMA.
// LDS limb planes [128][32] bf16: frag reads cover contiguous 1024B per
// 16-row group -> conflict-free by construction.
template <bool GATHER>
__global__ __launch_bounds__(256, 2) void gemm_split6_kernel(
    const float* __restrict__ A, const float* __restrict__ mfrp,
    const float* __restrict__ W, const float* __restrict__ bias,
    float* __restrict__ C, int M, int N, int K) {
  __shared__ __align__(16) unsigned short Apl[3][128][32];
  __shared__ __align__(16) unsigned short Bpl[3][128][32];
  const int t = threadIdx.x;
  const int m0 = blockIdx.y * 128;   // y = m-tile (slow) -> A-panel L2/L3 reuse
  const int n0 = blockIdx.x * 128;   // x = n-tile (fast)
  const int wid = t >> 6;
  const int l = t & 63;
  const int wm = wid >> 1, wn = wid & 1;
  const int lr = l & 15, lc = l >> 4;
  const int srow = t >> 3;   // staging row 0..31 (+32*it)
  const int skq = t & 7;     // staging k-quarter (float4 at k = skq*4)

  f32x4 acc[4][4];
#pragma unroll
  for (int i = 0; i < 4; ++i)
#pragma unroll
    for (int j = 0; j < 4; ++j) acc[i][j] = (f32x4){0.f, 0.f, 0.f, 0.f};

  const int nk = (K + 31) >> 5;

  float4 fA[4], fB[4];
  auto load_tiles = [&](int kt) {
    const int k = kt * 32 + skq * 4;
#pragma unroll
    for (int it = 0; it < 4; ++it) {
      const int row = srow + it * 32;
      float4 va = {0.f, 0.f, 0.f, 0.f};
      if (GATHER) {
        if (k < 512) va = *(const float4*)(A + (size_t)(m0 + row) * 512 + k);
        else if (k < 580) va = *(const float4*)(mfrp + (size_t)(m0 + row) * 68 + (k - 512));
      } else {
        if (k < K) va = *(const float4*)(A + (size_t)(m0 + row) * (size_t)K + k);
      }
      fA[it] = va;
      float4 vb = {0.f, 0.f, 0.f, 0.f};
      const int brow = n0 + row;
      if (k < K && brow < N) vb = *(const float4*)(W + (size_t)brow * (size_t)K + k);
      fB[it] = vb;
    }
  };

  load_tiles(0);
  for (int kt = 0; kt < nk; ++kt) {
    // split fp32 -> 3 bf16 limbs
    ushort4 sA[4][3], sB[4][3];
#pragma unroll
    for (int it = 0; it < 4; ++it) {
      const float fv[4] = {fA[it].x, fA[it].y, fA[it].z, fA[it].w};
      const float gw[4] = {fB[it].x, fB[it].y, fB[it].z, fB[it].w};
      unsigned short a0[4], a1[4], a2[4], b0[4], b1[4], b2[4];
#pragma unroll
      for (int u = 0; u < 4; ++u) {
        a0[u] = f2bf_rne(fv[u]);
        float r = fv[u] - bf2f(a0[u]);
        a1[u] = f2bf_rne(r);
        r -= bf2f(a1[u]);
        a2[u] = f2bf_rne(r);
        b0[u] = f2bf_rne(gw[u]);
        float s = gw[u] - bf2f(b0[u]);
        b1[u] = f2bf_rne(s);
        s -= bf2f(b1[u]);
        b2[u] = f2bf_rne(s);
      }
      sA[it][0] = {a0[0], a0[1], a0[2], a0[3]};
      sA[it][1] = {a1[0], a1[1], a1[2], a1[3]};
      sA[it][2] = {a2[0], a2[1], a2[2], a2[3]};
      sB[it][0] = {b0[0], b0[1], b0[2], b0[3]};
      sB[it][1] = {b1[0], b1[1], b1[2], b1[3]};
      sB[it][2] = {b2[0], b2[1], b2[2], b2[3]};
    }
    __syncthreads();   // previous compute fully consumed LDS
#pragma unroll
    for (int it = 0; it < 4; ++it) {
      const int row = srow + it * 32;
#pragma unroll
      for (int p = 0; p < 3; ++p) {
        *(ushort4*)&Apl[p][row][skq * 4] = sA[it][p];
        *(ushort4*)&Bpl[p][row][skq * 4] = sB[it][p];
      }
    }
    __syncthreads();
    if (kt + 1 < nk) load_tiles(kt + 1);  // issue next loads under compute

    // compute: 96 MFMAs (6 limb combos x 4x4 frags), small->large limbs
    s16x8 bf[3][4];
#pragma unroll
    for (int q = 0; q < 3; ++q)
#pragma unroll
      for (int j = 0; j < 4; ++j)
        bf[q][j] = *(const s16x8*)&Bpl[q][wn * 64 + j * 16 + lr][lc * 8];
#pragma unroll
    for (int i = 0; i < 4; ++i) {
      const int ar = wm * 64 + i * 16 + lr;
      const s16x8 a0 = *(const s16x8*)&Apl[0][ar][lc * 8];
      const s16x8 a1 = *(const s16x8*)&Apl[1][ar][lc * 8];
      const s16x8 a2 = *(const s16x8*)&Apl[2][ar][lc * 8];
#pragma unroll
      for (int j = 0; j < 4; ++j) {
        f32x4 c = acc[i][j];
        c = __builtin_amdgcn_mfma_f32_16x16x32_bf16(a2, bf[0][j], c, 0, 0, 0);
        c = __builtin_amdgcn_mfma_f32_16x16x32_bf16(a1, bf[1][j], c, 0, 0, 0);
        c = __builtin_amdgcn_mfma_f32_16x16x32_bf16(a0, bf[2][j], c, 0, 0, 0);
        c = __builtin_amdgcn_mfma_f32_16x16x32_bf16(a1, bf[0][j], c, 0, 0, 0);
        c = __builtin_amdgcn_mfma_f32_16x16x32_bf16(a0, bf[1][j], c, 0, 0, 0);
        c = __builtin_amdgcn_mfma_f32_16x16x32_bf16(a0, bf[0][j], c, 0, 0, 0);
        acc[i][j] = c;
      }
    }
  }
  // epilogue: D layout col=lane&15, row=(lane>>4)*4+reg  [m89-verified]
#pragma unroll
  for (int j = 0; j < 4; ++j) {
    const int n = n0 + wn * 64 + j * 16 + lr;
    if (n < N) {
      const float bz = bias[n];
#pragma unroll
      for (int i = 0; i < 4; ++i) {
        const int mb = m0 + wm * 64 + i * 16 + lc * 4;
#pragma unroll
        for (int r = 0; r < 4; ++r)
          C[(size_t)(mb + r) * (size_t)N + n] = acc[i][j][r] + bz;
      }
    }
  }
}

// ---------- 2b) fp32 tiled GEMM (kept for G3, N=64 last layer) ----------
template <bool GATHER>
__global__ __launch_bounds__(256, 4) void gemm128_kernel(
    const float* __restrict__ A, const float* __restrict__ mfrp,
    const float* __restrict__ W, const float* __restrict__ bias,
    float* __restrict__ C, int M, int N, int K) {
  __shared__ float As[16][132];
  __shared__ float Bs[16][132];
  const int t = threadIdx.x;
  const int m0 = blockIdx.x * 128;
  const int n0 = blockIdx.y * 128;
  const int tx = t & 15, ty = t >> 4;
  const int srow = t >> 1;
  const int skc = (t & 1) * 8;

  float acc[2][2][4][4] = {};
  const int nk = (K + 15) >> 4;
  const int arow = m0 + srow;
  const int brow = n0 + srow;
  const bool bvalid = brow < N;

  for (int kt = 0; kt < nk; ++kt) {
    const int k0 = kt * 16;
    float4 av[2], bv[2];
#pragma unroll
    for (int c = 0; c < 2; ++c) {
      const int k = k0 + skc + c * 4;
      float4 va = {0.f, 0.f, 0.f, 0.f};
      if (GATHER) {
        if (k < 512) va = *(const float4*)(A + (size_t)arow * 512 + k);
        else if (k < 580) va = *(const float4*)(mfrp + (size_t)arow * 68 + (k - 512));
      } else {
        if (k < K) va = *(const float4*)(A + (size_t)arow * K + k);
      }
      av[c] = va;
      float4 vb = {0.f, 0.f, 0.f, 0.f};
      if (bvalid && k < K) vb = *(const float4*)(W + (size_t)brow * K + k);
      bv[c] = vb;
    }
    __syncthreads();
#pragma unroll
    for (int c = 0; c < 2; ++c) {
      As[skc + c * 4 + 0][srow] = av[c].x;
      As[skc + c * 4 + 1][srow] = av[c].y;
      As[skc + c * 4 + 2][srow] = av[c].z;
      As[skc + c * 4 + 3][srow] = av[c].w;
      Bs[skc + c * 4 + 0][srow] = bv[c].x;
      Bs[skc + c * 4 + 1][srow] = bv[c].y;
      Bs[skc + c * 4 + 2][srow] = bv[c].z;
      Bs[skc + c * 4 + 3][srow] = bv[c].w;
    }
    __syncthreads();
#pragma unroll
    for (int k = 0; k < 16; ++k) {
      const float4 a0 = *(const float4*)&As[k][ty << 2];
      const float4 a1 = *(const float4*)&As[k][(ty << 2) + 64];
      const float4 b0 = *(const float4*)&Bs[k][tx << 2];
      const float4 b1 = *(const float4*)&Bs[k][(tx << 2) + 64];
      const float aa[2][4] = {{a0.x, a0.y, a0.z, a0.w}, {a1.x, a1.y, a1.z, a1.w}};
      const float bb[2][4] = {{b0.x, b0.y, b0.z, b0.w}, {b1.x, b1.y, b1.z, b1.w}};
#pragma unroll
      for (int i2 = 0; i2 < 2; ++i2)
#pragma unroll
        for (int i = 0; i < 4; ++i)
#pragma unroll
          for (int j2 = 0; j2 < 2; ++j2)
#pragma unroll
            for (int j = 0; j < 4; ++j)
              acc[i2][j2][i][j] = fmaf(aa[i2][i], bb[j2][j], acc[i2][j2][i][j]);
    }
  }
#pragma unroll
  for (int j2 = 0; j2 < 2; ++j2) {
    const int n = n0 + j2 * 64 + (tx << 2);
    if (n < N) {
      const float4 bz = *(const float4*)(bias + n);
#pragma unroll
      for (int i2 = 0; i2 < 2; ++i2)
#pragma unroll
        for (int i = 0; i < 4; ++i) {
          const int m = m0 + i2 * 64 + (ty << 2) + i;
          float4 o;
          o.x = acc[i2][j2][i][0] + bz.x;
          o.y = acc[i2][j2][i][1] + bz.y;
          o.z = acc[i2][j2][i][2] + bz.z;
          o.w = acc[i2][j2][i][3] + bz.w;
          *(float4*)(C + (size_t)m * N + n) = o;
        }
    }
  }
}

// ---------- 3) in-place row LayerNorm + exact GELU ----------
__global__ __launch_bounds__(256) void ln_gelu_kernel(
    float* __restrict__ Z, const float* __restrict__ gamma,
    const float* __restrict__ beta, const int N) {
  __shared__ float sred[4];
  const int t = threadIdx.x;
  float* zr = Z + (size_t)blockIdx.x * N;
  float vals[5];
  float s = 0.f;
#pragma unroll
  for (int c = 0; c < 5; ++c) {
    const int i = t + c * 256;
    const float v = (i < N) ? zr[i] : 0.f;
    vals[c] = v;
    s += v;
  }
  s = wsum64(s);
  if ((t & 63) == 0) sred[t >> 6] = s;
  __syncthreads();
  const float mu = (sred[0] + sred[1] + sred[2] + sred[3]) / (float)N;
  __syncthreads();
  float q = 0.f;
#pragma unroll
  for (int c = 0; c < 5; ++c) {
    const int i = t + c * 256;
    if (i < N) {
      const float d = vals[c] - mu;
      q += d * d;
    }
  }
  q = wsum64(q);
  if ((t & 63) == 0) sred[t >> 6] = q;
  __syncthreads();
  const float var = (sred[0] + sred[1] + sred[2] + sred[3]) / (float)N;
  const float rstd = 1.f / sqrtf(var + 1e-5f);
#pragma unroll
  for (int c = 0; c < 5; ++c) {
    const int i = t + c * 256;
    if (i < N) {
      const float y = (vals[c] - mu) * rstd * gamma[i] + beta[i];
      zr[i] = 0.5f * y * (1.f + erff(y * 0.70710678118654752f));
    }
  }
}

// ---------- 4) final: +rp*spec^T, noise, top-2, gates, partials ----------
__global__ __launch_bounds__(256) void final_kernel(
    const float* __restrict__ clean, const float* __restrict__ mfrp,
    const float* __restrict__ nsc, const float* __restrict__ noise,
    const float* __restrict__ spec, float* __restrict__ out,
    float* __restrict__ pg, float* __restrict__ pl) {
  const int t = threadIdx.x;
  const int w = t >> 6;
  const int e = t & 63;
  __shared__ float sg[4][64];
  __shared__ float sl[4][64];
  const float4 sp = *(const float4*)(spec + e * 4);
  float accg = 0.f, accl = 0.f;
  for (int it = 0; it < 16; ++it) {
    const int row = blockIdx.x * 64 + it * 4 + w;
    const float4 rp = *(const float4*)(mfrp + (size_t)row * 68 + 64);
    float c = clean[(size_t)row * 64 + e];
    c += rp.x * sp.x + rp.y * sp.y + rp.z * sp.z + rp.w * sp.w;
    const float nv = noise[(size_t)row * 64 + e];
    const float noisy = c + nv * nsc[row];
    float v = noisy;
    int ix = e;
#pragma unroll
    for (int off = 32; off; off >>= 1) {
      const float ov = __shfl_xor(v, off);
      const int oi = __shfl_xor(ix, off);
      if (ov > v || (ov == v && oi < ix)) { v = ov; ix = oi; }
    }
    const float v1 = v;
    const int i1 = ix;
    float v2 = (e == i1) ? -FLT_MAX : noisy;
    int ix2 = e;
#pragma unroll
    for (int off = 32; off; off >>= 1) {
      const float ov = __shfl_xor(v2, off);
      const int oi = __shfl_xor(ix2, off);
      if (ov > v2 || (ov == v2 && oi < ix2)) { v2 = ov; ix2 = oi; }
    }
    const int i2 = ix2;
    if (e == 0) {
      const float texp = expf(v2 - v1);
      const float tw0 = 1.f / (1.f + texp);
      out[(size_t)row * 2 + 0] = tw0;
      out[(size_t)row * 2 + 1] = texp * tw0;
      out[32768 + (size_t)row * 2 + 0] = (float)i1;
      out[32768 + (size_t)row * 2 + 1] = (float)i2;
    }
    const float mx = wmax64(c);
    const float p = expf(c - mx);
    const float ssum = wsum64(p);
    accg += p / ssum;
    accl += (e == i1 || e == i2) ? 1.f : 0.f;
  }
  sg[w][e] = accg;
  sl[w][e] = accl;
  __syncthreads();
  if (t < 64) {
    pg[blockIdx.x * 64 + t] = sg[0][t] + sg[1][t] + sg[2][t] + sg[3][t];
    pl[blockIdx.x * 64 + t] = sl[0][t] + sl[1][t] + sl[2][t] + sl[3][t];
  }
}

// ---------- 5) aux loss ----------
__global__ void loss_kernel(const float* __restrict__ pg,
                            const float* __restrict__ pl,
                            float* __restrict__ out) {
  const int e = threadIdx.x;  // 64 threads
  float g = 0.f, l = 0.f;
  for (int b = 0; b < 256; ++b) {
    g += pg[b * 64 + e];
    l += pl[b * 64 + e];
  }
  const float prob = g * (1.f / 16384.f);
  const float ld = l * (1.f / 16384.f);
  const float load_loss = 64.f * wsum64(prob * ld);
  const float sgs = wsum64(g);
  const float mean = sgs * (1.f / 64.f);
  const float d = g - mean;
  const float var = wsum64(d * d) * (1.f / 63.f);
  if (e == 0) out[65536] = 0.01f * load_loss + 0.01f * (var / mean);
}

extern "C" void kernel_launch(void* const* d_in, const int* in_sizes, int n_in,
                              void* d_out, int out_size, void* d_ws, size_t ws_size,
                              hipStream_t stream) {
  (void)in_sizes; (void)n_in; (void)out_size; (void)ws_size;
  const float* x = (const float*)d_in[0];
  const float* noise = (const float*)d_in[1];
  const float* vol_w = (const float*)d_in[2];
  const float* vol_b = (const float*)d_in[3];
  const float* vol_g = (const float*)d_in[4];
  const float* vol_bb = (const float*)d_in[5];
  const float* trend_w = (const float*)d_in[6];
  const float* trend_b = (const float*)d_in[7];
  const float* trend_g = (const float*)d_in[8];
  const float* trend_bb = (const float*)d_in[9];
  const float* mom_w = (const float*)d_in[10];
  const float* mom_b = (const float*)d_in[11];
  const float* mom_g = (const float*)d_in[12];
  const float* mom_bb = (const float*)d_in[13];
  const float* reg_w = (const float*)d_in[14];
  const float* reg_b = (const float*)d_in[15];
  const float* reg_g = (const float*)d_in[16];
  const float* reg_bb = (const float*)d_in[17];
  const float* rc1_w = (const float*)d_in[18];
  const float* rc1_b = (const float*)d_in[19];
  const float* rc2_w = (const float*)d_in[20];
  const float* rc2_b = (const float*)d_in[21];
  const float* g1_w = (const float*)d_in[22];
  const float* g1_b = (const float*)d_in[23];
  const float* g1_g = (const float*)d_in[24];
  const float* g1_bb = (const float*)d_in[25];
  const float* g2_w = (const float*)d_in[26];
  const float* g2_b = (const float*)d_in[27];
  const float* g2_g = (const float*)d_in[28];
  const float* g2_bb = (const float*)d_in[29];
  const float* g3_w = (const float*)d_in[30];
  const float* g3_b = (const float*)d_in[31];
  const float* ns1_w = (const float*)d_in[32];
  const float* ns1_b = (const float*)d_in[33];
  const float* ns2_w = (const float*)d_in[34];
  const float* ns2_b = (const float*)d_in[35];
  const float* spec = (const float*)d_in[36];
  float* out = (float*)d_out;

  const int B = BROWS;
  float* ws = (float*)d_ws;
  float* mfrp = ws;                   // B*68
  float* nsc = mfrp + (size_t)B * 68; // B
  float* z1 = nsc + B;                // B*1160
  float* z2 = z1 + (size_t)B * 1160;  // B*580
  float* cln = z2 + (size_t)B * 580;  // B*64
  float* pg = cln + (size_t)B * 64;   // 256*64
  float* pl = pg + 256 * 64;          // 256*64

  encoder_kernel<<<1024, 256, 0, stream>>>(
      x, vol_w, vol_b, vol_g, vol_bb, trend_w, trend_b, trend_g, trend_bb,
      mom_w, mom_b, mom_g, mom_bb, reg_w, reg_b, reg_g, reg_bb,
      rc1_w, rc1_b, rc2_w, rc2_b, ns1_w, ns1_b, ns2_w, ns2_b, mfrp, nsc);

  // G1: [16384,580] x [1160,580]^T -> z1   (split-bf16x6 MFMA)
  gemm_split6_kernel<true><<<dim3(10, 128), 256, 0, stream>>>(
      x, mfrp, g1_w, g1_b, z1, B, 1160, 580);
  ln_gelu_kernel<<<B, 256, 0, stream>>>(z1, g1_g, g1_bb, 1160);

  // G2: [16384,1160] x [580,1160]^T -> z2  (split-bf16x6 MFMA)
  gemm_split6_kernel<false><<<dim3(5, 128), 256, 0, stream>>>(
      z1, nullptr, g2_w, g2_b, z2, B, 580, 1160);
  ln_gelu_kernel<<<B, 256, 0, stream>>>(z2, g2_g, g2_bb, 580);

  // G3: [16384,580] x [64,580]^T -> clean  (fp32, last layer)
  gemm128_kernel<false><<<dim3(128, 1), 256, 0, stream>>>(
      z2, nullptr, g3_w, g3_b, cln, B, 64, 580);

  final_kernel<<<256, 256, 0, stream>>>(cln, mfrp, nsc, noise, spec, out, pg, pl);
  loss_kernel<<<1, 64, 0, stream>>>(pg, pl, out);
}

// Round 4
// 608.815 us; speedup vs baseline: 1.8651x; 1.0801x over previous
//
#include <hip/hip_runtime.h>
#include <hip/hip_fp16.h>
#include <cfloat>

#define BROWS 16384

typedef float f32x4 __attribute__((ext_vector_type(4)));
typedef _Float16 f16x8 __attribute__((ext_vector_type(8)));

// ---------- wave helpers ----------
__device__ __forceinline__ float wsum64(float v) {
#pragma unroll
  for (int off = 32; off; off >>= 1) v += __shfl_xor(v, off);
  return v;
}
__device__ __forceinline__ float wmax64(float v) {
#pragma unroll
  for (int off = 32; off; off >>= 1) v = fmaxf(v, __shfl_xor(v, off));
  return v;
}
__device__ __forceinline__ float gsum16(float v) {
#pragma unroll
  for (int off = 1; off < 16; off <<= 1) v += __shfl_xor(v, off);
  return v;
}

// fp16 2-limb split: v ~= h0 + 2^-11 * h1, residual <= 2^-24 |v|
__device__ __forceinline__ void split2(float v, unsigned short& o0, unsigned short& o1) {
  const _Float16 h0 = (_Float16)v;
  const float r = (v - (float)h0) * 2048.0f;
  const _Float16 h1 = (_Float16)r;
  o0 = __builtin_bit_cast(unsigned short, h0);
  o1 = __builtin_bit_cast(unsigned short, h1);
}

// async global -> LDS, 16B per lane, dest = lds_base + lane*16
__device__ __forceinline__ void gll16(const unsigned short* g, unsigned short* l) {
  __builtin_amdgcn_global_load_lds(
      (const __attribute__((address_space(1))) unsigned int*)g,
      (__attribute__((address_space(3))) unsigned int*)l, 16, 0, 0);
}

// ---------- 1) market encoder + router + noise-scale ----------
__global__ __launch_bounds__(256) void encoder_kernel(
    const float* __restrict__ x,
    const float* __restrict__ vol_w, const float* __restrict__ vol_b,
    const float* __restrict__ vol_g, const float* __restrict__ vol_bb,
    const float* __restrict__ trend_w, const float* __restrict__ trend_b,
    const float* __restrict__ trend_g, const float* __restrict__ trend_bb,
    const float* __restrict__ mom_w, const float* __restrict__ mom_b,
    const float* __restrict__ mom_g, const float* __restrict__ mom_bb,
    const float* __restrict__ reg_w, const float* __restrict__ reg_b,
    const float* __restrict__ reg_g, const float* __restrict__ reg_bb,
    const float* __restrict__ rc1_w, const float* __restrict__ rc1_b,
    const float* __restrict__ rc2_w, const float* __restrict__ rc2_b,
    const float* __restrict__ ns1_w, const float* __restrict__ ns1_b,
    const float* __restrict__ ns2_w, const float* __restrict__ ns2_b,
    float* __restrict__ mfrp, float* __restrict__ nsc) {
  const int t = threadIdx.x;
  const int w = t >> 6;
  const int e = t & 63;
  const int br = e >> 4;
  const int rowbase = blockIdx.x * 16 + w * 4;
  const int rb = __builtin_amdgcn_readfirstlane(rowbase);

  const float* wsel = (br == 0) ? vol_w : (br == 1) ? trend_w : (br == 2) ? mom_w : reg_w;
  const float* bsel = (br == 0) ? vol_b : (br == 1) ? trend_b : (br == 2) ? mom_b : reg_b;
  const float* gsel = (br == 0) ? vol_g : (br == 1) ? trend_g : (br == 2) ? mom_g : reg_g;
  const float* bbsel = (br == 0) ? vol_bb : (br == 1) ? trend_bb : (br == 2) ? mom_bb : reg_bb;
  const float* wrow = wsel + (size_t)(e & 15) * 512;

  float acc0 = 0.f, acc1 = 0.f, acc2 = 0.f, acc3 = 0.f;
  const float* xr = x + (size_t)rb * 512;
  for (int k = 0; k < 512; k += 4) {
    const float4 wv = *(const float4*)(wrow + k);
    const float4 x0 = *(const float4*)(xr + k);
    const float4 x1 = *(const float4*)(xr + 512 + k);
    const float4 x2 = *(const float4*)(xr + 1024 + k);
    const float4 x3 = *(const float4*)(xr + 1536 + k);
    acc0 += wv.x * x0.x + wv.y * x0.y + wv.z * x0.z + wv.w * x0.w;
    acc1 += wv.x * x1.x + wv.y * x1.y + wv.z * x1.z + wv.w * x1.w;
    acc2 += wv.x * x2.x + wv.y * x2.y + wv.z * x2.z + wv.w * x2.w;
    acc3 += wv.x * x3.x + wv.y * x3.y + wv.z * x3.z + wv.w * x3.w;
  }
  const float bias = bsel[e & 15];
  const float gv = gsel[e & 15];
  const float bbv = bbsel[e & 15];

  __shared__ float smf[4][4][64];
  __shared__ float shid[4][4][32];
  __shared__ float srp[4][4][4];

  float vr[4] = {acc0 + bias, acc1 + bias, acc2 + bias, acc3 + bias};
#pragma unroll
  for (int r = 0; r < 4; ++r) {
    const float v = fmaxf(vr[r], 0.f);
    const float mu = gsum16(v) * (1.f / 16.f);
    const float d = v - mu;
    const float var = gsum16(d * d) * (1.f / 16.f);
    const float mfv = d * (1.f / sqrtf(var + 1e-5f)) * gv + bbv;
    mfrp[(size_t)(rowbase + r) * 68 + e] = mfv;
    smf[w][r][e] = mfv;
  }
  __syncthreads();
  if (e < 32) {
#pragma unroll
    for (int r = 0; r < 4; ++r) {
      float h = rc1_b[e];
#pragma unroll 8
      for (int j = 0; j < 64; ++j) h += rc1_w[e * 64 + j] * smf[w][r][j];
      shid[w][r][e] = fmaxf(h, 0.f);
    }
  }
  __syncthreads();
  if (e < 16) {
    const int r = e >> 2, l = e & 3;
    float z = rc2_b[l];
#pragma unroll 8
    for (int j = 0; j < 32; ++j) z += rc2_w[l * 32 + j] * shid[w][r][j];
    float mx = z;
    mx = fmaxf(mx, __shfl_xor(mx, 1));
    mx = fmaxf(mx, __shfl_xor(mx, 2));
    const float ex = expf(z - mx);
    float s = ex;
    s += __shfl_xor(s, 1);
    s += __shfl_xor(s, 2);
    const float rp = ex / s;
    srp[w][r][l] = rp;
    mfrp[(size_t)(rowbase + r) * 68 + 64 + l] = rp;
  }
  __syncthreads();
  if (e < 4) {
    const int r = e;
    const float rp0 = srp[w][r][0], rp1 = srp[w][r][1], rp2 = srp[w][r][2], rp3 = srp[w][r][3];
    float z = ns2_b[0];
#pragma unroll
    for (int i = 0; i < 16; ++i) {
      float h = ns1_b[i] + ns1_w[i * 4 + 0] * rp0 + ns1_w[i * 4 + 1] * rp1 +
                ns1_w[i * 4 + 2] * rp2 + ns1_w[i * 4 + 3] * rp3;
      z += ns2_w[i] * fmaxf(h, 0.f);
    }
    nsc[rowbase + r] = 1.f / (1.f + expf(-z));
  }
}

// ---------- splits: fp32 -> 2 fp16 limb planes (zero-padded) ----------
__global__ __launch_bounds__(256) void split_gi_kernel(
    const float* __restrict__ x, const float* __restrict__ mfrp,
    unsigned short* __restrict__ p0, unsigned short* __restrict__ p1) {
  const int row = blockIdx.x;
  const int Kp = 640;
#pragma unroll
  for (int c = 0; c < 3; ++c) {
    const int i = threadIdx.x + c * 256;
    if (i < Kp) {
      float v = 0.f;
      if (i < 512) v = x[(size_t)row * 512 + i];
      else if (i < 580) v = mfrp[(size_t)row * 68 + (i - 512)];
      unsigned short h0, h1;
      split2(v, h0, h1);
      p0[(size_t)row * Kp + i] = h0;
      p1[(size_t)row * Kp + i] = h1;
    }
  }
}

__global__ __launch_bounds__(256) void split_w_kernel(
    const float* __restrict__ W, unsigned short* __restrict__ p0,
    unsigned short* __restrict__ p1, int N, int K, int Kp) {
  const int n = blockIdx.x;  // over padded rows
  for (int i = threadIdx.x; i < Kp; i += 256) {
    const float v = (n < N && i < K) ? W[(size_t)n * K + i] : 0.f;
    unsigned short h0, h1;
    split2(v, h0, h1);
    p0[(size_t)n * Kp + i] = h0;
    p1[(size_t)n * Kp + i] = h1;
  }
}

// ---------- 2) fp16x3 MFMA GEMM: C = A*W^T + bias ----------
// A,W pre-split into 2 fp16 limb planes (limb1 scaled by 2^11).
// C = A0B0 + 2^-11*(A1B0 + A0B1); dropped A1B1 term ~2^-24 rel.
// Tile 128x128, BK=64, 4 waves (2x2 of 64x64), 16x16x32 f16 MFMA,
// global_load_lds(16B) staging into linear LDS (m97 structure).
__global__ __launch_bounds__(256, 2) void gemm_fp16x3_kernel(
    const unsigned short* __restrict__ Ap0, const unsigned short* __restrict__ Ap1,
    const unsigned short* __restrict__ Bp0, const unsigned short* __restrict__ Bp1,
    const float* __restrict__ bias, float* __restrict__ C,
    int N, int Kp, int ldc) {
  __shared__ __align__(16) unsigned short As[128][64];
  __shared__ __align__(16) unsigned short Bs[128][64];
  const int t = threadIdx.x;
  const int w = t >> 6, l = t & 63;
  const int wm = w >> 1, wn = w & 1;
  const int lr = l & 15, lc = l >> 4;
  const int m0 = blockIdx.y * 128;
  const int n0 = blockIdx.x * 128;
  const int arow = l >> 3;        // 0..7 within 8-row staging group
  const int acol = (l & 7) * 8;   // fp16 element offset (16B chunks)

  f32x4 accM[4][4], accL[4][4];
#pragma unroll
  for (int i = 0; i < 4; ++i)
#pragma unroll
    for (int j = 0; j < 4; ++j) {
      accM[i][j] = (f32x4){0.f, 0.f, 0.f, 0.f};
      accL[i][j] = (f32x4){0.f, 0.f, 0.f, 0.f};
    }

  const unsigned short* Aseg[3] = {Ap0, Ap1, Ap0};
  const unsigned short* Bseg[3] = {Bp0, Bp0, Bp1};
  const int KT = Kp >> 6;

  for (int seg = 0; seg < 3; ++seg) {
    const unsigned short* Ab = Aseg[seg];
    const unsigned short* Bb = Bseg[seg];
    for (int kt = 0; kt < KT; ++kt) {
      const int kk = kt * 64 + acol;
      __syncthreads();  // previous compute fully consumed LDS
#pragma unroll
      for (int r = 0; r < 4; ++r) {
        const int rowb = r * 32 + w * 8;
        gll16(Ab + (size_t)(m0 + rowb + arow) * Kp + kk, &As[rowb][0]);
        gll16(Bb + (size_t)(n0 + rowb + arow) * Kp + kk, &Bs[rowb][0]);
      }
      __syncthreads();  // drains vmcnt(0): tiles visible
      f16x8 af[2][4], bf[2][4];
#pragma unroll
      for (int ks = 0; ks < 2; ++ks)
#pragma unroll
        for (int i = 0; i < 4; ++i) {
          af[ks][i] = *(const f16x8*)&As[wm * 64 + i * 16 + lr][ks * 32 + lc * 8];
          bf[ks][i] = *(const f16x8*)&Bs[wn * 64 + i * 16 + lr][ks * 32 + lc * 8];
        }
      if (seg == 0) {
#pragma unroll
        for (int ks = 0; ks < 2; ++ks)
#pragma unroll
          for (int i = 0; i < 4; ++i)
#pragma unroll
            for (int j = 0; j < 4; ++j)
              accM[i][j] = __builtin_amdgcn_mfma_f32_16x16x32_f16(
                  af[ks][i], bf[ks][j], accM[i][j], 0, 0, 0);
      } else {
#pragma unroll
        for (int ks = 0; ks < 2; ++ks)
#pragma unroll
          for (int i = 0; i < 4; ++i)
#pragma unroll
            for (int j = 0; j < 4; ++j)
              accL[i][j] = __builtin_amdgcn_mfma_f32_16x16x32_f16(
                  af[ks][i], bf[ks][j], accL[i][j], 0, 0, 0);
      }
    }
  }
  // epilogue: D layout col(lane&15)=n, row((lane>>4)*4+reg)=m  [R2-verified]
#pragma unroll
  for (int j = 0; j < 4; ++j) {
    const int n = n0 + wn * 64 + j * 16 + lr;
    if (n < N) {
      const float bz = bias[n];
#pragma unroll
      for (int i = 0; i < 4; ++i) {
        const int mb = m0 + wm * 64 + i * 16 + lc * 4;
#pragma unroll
        for (int r = 0; r < 4; ++r)
          C[(size_t)(mb + r) * (size_t)ldc + n] =
              accM[i][j][r] + 0.00048828125f * accL[i][j][r] + bz;
      }
    }
  }
}

// ---------- 2b) fp32 tiled GEMM (G3, N=64 last layer) ----------
template <bool GATHER>
__global__ __launch_bounds__(256, 4) void gemm128_kernel(
    const float* __restrict__ A, const float* __restrict__ mfrp,
    const float* __restrict__ W, const float* __restrict__ bias,
    float* __restrict__ C, int M, int N, int K) {
  __shared__ float As[16][132];
  __shared__ float Bs[16][132];
  const int t = threadIdx.x;
  const int m0 = blockIdx.x * 128;
  const int n0 = blockIdx.y * 128;
  const int tx = t & 15, ty = t >> 4;
  const int srow = t >> 1;
  const int skc = (t & 1) * 8;

  float acc[2][2][4][4] = {};
  const int nk = (K + 15) >> 4;
  const int arow = m0 + srow;
  const int brow = n0 + srow;
  const bool bvalid = brow < N;

  for (int kt = 0; kt < nk; ++kt) {
    const int k0 = kt * 16;
    float4 av[2], bv[2];
#pragma unroll
    for (int c = 0; c < 2; ++c) {
      const int k = k0 + skc + c * 4;
      float4 va = {0.f, 0.f, 0.f, 0.f};
      if (GATHER) {
        if (k < 512) va = *(const float4*)(A + (size_t)arow * 512 + k);
        else if (k < 580) va = *(const float4*)(mfrp + (size_t)arow * 68 + (k - 512));
      } else {
        if (k < K) va = *(const float4*)(A + (size_t)arow * K + k);
      }
      av[c] = va;
      float4 vb = {0.f, 0.f, 0.f, 0.f};
      if (bvalid && k < K) vb = *(const float4*)(W + (size_t)brow * K + k);
      bv[c] = vb;
    }
    __syncthreads();
#pragma unroll
    for (int c = 0; c < 2; ++c) {
      As[skc + c * 4 + 0][srow] = av[c].x;
      As[skc + c * 4 + 1][srow] = av[c].y;
      As[skc + c * 4 + 2][srow] = av[c].z;
      As[skc + c * 4 + 3][srow] = av[c].w;
      Bs[skc + c * 4 + 0][srow] = bv[c].x;
      Bs[skc + c * 4 + 1][srow] = bv[c].y;
      Bs[skc + c * 4 + 2][srow] = bv[c].z;
      Bs[skc + c * 4 + 3][srow] = bv[c].w;
    }
    __syncthreads();
#pragma unroll
    for (int k = 0; k < 16; ++k) {
      const float4 a0 = *(const float4*)&As[k][ty << 2];
      const float4 a1 = *(const float4*)&As[k][(ty << 2) + 64];
      const float4 b0 = *(const float4*)&Bs[k][tx << 2];
      const float4 b1 = *(const float4*)&Bs[k][(tx << 2) + 64];
      const float aa[2][4] = {{a0.x, a0.y, a0.z, a0.w}, {a1.x, a1.y, a1.z, a1.w}};
      const float bb[2][4] = {{b0.x, b0.y, b0.z, b0.w}, {b1.x, b1.y, b1.z, b1.w}};
#pragma unroll
      for (int i2 = 0; i2 < 2; ++i2)
#pragma unroll
        for (int i = 0; i < 4; ++i)
#pragma unroll
          for (int j2 = 0; j2 < 2; ++j2)
#pragma unroll
            for (int j = 0; j < 4; ++j)
              acc[i2][j2][i][j] = fmaf(aa[i2][i], bb[j2][j], acc[i2][j2][i][j]);
    }
  }
#pragma unroll
  for (int j2 = 0; j2 < 2; ++j2) {
    const int n = n0 + j2 * 64 + (tx << 2);
    if (n < N) {
      const float4 bz = *(const float4*)(bias + n);
#pragma unroll
      for (int i2 = 0; i2 < 2; ++i2)
#pragma unroll
        for (int i = 0; i < 4; ++i) {
          const int m = m0 + i2 * 64 + (ty << 2) + i;
          float4 o;
          o.x = acc[i2][j2][i][0] + bz.x;
          o.y = acc[i2][j2][i][1] + bz.y;
          o.z = acc[i2][j2][i][2] + bz.z;
          o.w = acc[i2][j2][i][3] + bz.w;
          *(float4*)(C + (size_t)m * N + n) = o;
        }
    }
  }
}

// ---------- 3a) row LayerNorm + exact GELU -> fp16 limb planes (z1) ----------
__global__ __launch_bounds__(256) void ln_gelu_split_kernel(
    const float* __restrict__ Z, const float* __restrict__ gamma,
    const float* __restrict__ beta, unsigned short* __restrict__ p0,
    unsigned short* __restrict__ p1) {
  const int N = 1160, Kp = 1216;
  __shared__ float sred[4];
  const int t = threadIdx.x;
  const float* zr = Z + (size_t)blockIdx.x * N;
  float vals[5];
  float s = 0.f;
#pragma unroll
  for (int c = 0; c < 5; ++c) {
    const int i = t + c * 256;
    const float v = (i < N) ? zr[i] : 0.f;
    vals[c] = v;
    s += v;
  }
  s = wsum64(s);
  if ((t & 63) == 0) sred[t >> 6] = s;
  __syncthreads();
  const float mu = (sred[0] + sred[1] + sred[2] + sred[3]) / (float)N;
  __syncthreads();
  float q = 0.f;
#pragma unroll
  for (int c = 0; c < 5; ++c) {
    const int i = t + c * 256;
    if (i < N) {
      const float d = vals[c] - mu;
      q += d * d;
    }
  }
  q = wsum64(q);
  if ((t & 63) == 0) sred[t >> 6] = q;
  __syncthreads();
  const float var = (sred[0] + sred[1] + sred[2] + sred[3]) / (float)N;
  const float rstd = 1.f / sqrtf(var + 1e-5f);
#pragma unroll
  for (int c = 0; c < 5; ++c) {
    const int i = t + c * 256;
    if (i < Kp) {
      float g = 0.f;
      if (i < N) {
        const float y = (vals[c] - mu) * rstd * gamma[i] + beta[i];
        g = 0.5f * y * (1.f + erff(y * 0.70710678118654752f));
      }
      unsigned short h0, h1;
      split2(g, h0, h1);
      p0[(size_t)blockIdx.x * Kp + i] = h0;
      p1[(size_t)blockIdx.x * Kp + i] = h1;
    }
  }
}

// ---------- 3b) in-place row LayerNorm + exact GELU (z2) ----------
__global__ __launch_bounds__(256) void ln_gelu_kernel(
    float* __restrict__ Z, const float* __restrict__ gamma,
    const float* __restrict__ beta, const int N) {
  __shared__ float sred[4];
  const int t = threadIdx.x;
  float* zr = Z + (size_t)blockIdx.x * N;
  float vals[5];
  float s = 0.f;
#pragma unroll
  for (int c = 0; c < 5; ++c) {
    const int i = t + c * 256;
    const float v = (i < N) ? zr[i] : 0.f;
    vals[c] = v;
    s += v;
  }
  s = wsum64(s);
  if ((t & 63) == 0) sred[t >> 6] = s;
  __syncthreads();
  const float mu = (sred[0] + sred[1] + sred[2] + sred[3]) / (float)N;
  __syncthreads();
  float q = 0.f;
#pragma unroll
  for (int c = 0; c < 5; ++c) {
    const int i = t + c * 256;
    if (i < N) {
      const float d = vals[c] - mu;
      q += d * d;
    }
  }
  q = wsum64(q);
  if ((t & 63) == 0) sred[t >> 6] = q;
  __syncthreads();
  const float var = (sred[0] + sred[1] + sred[2] + sred[3]) / (float)N;
  const float rstd = 1.f / sqrtf(var + 1e-5f);
#pragma unroll
  for (int c = 0; c < 5; ++c) {
    const int i = t + c * 256;
    if (i < N) {
      const float y = (vals[c] - mu) * rstd * gamma[i] + beta[i];
      zr[i] = 0.5f * y * (1.f + erff(y * 0.70710678118654752f));
    }
  }
}

// ---------- 4) final: +rp*spec^T, noise, top-2, gates, partials ----------
__global__ __launch_bounds__(256) void final_kernel(
    const float* __restrict__ clean, const float* __restrict__ mfrp,
    const float* __restrict__ nsc, const float* __restrict__ noise,
    const float* __restrict__ spec, float* __restrict__ out,
    float* __restrict__ pg, float* __restrict__ pl) {
  const int t = threadIdx.x;
  const int w = t >> 6;
  const int e = t & 63;
  __shared__ float sg[4][64];
  __shared__ float sl[4][64];
  const float4 sp = *(const float4*)(spec + e * 4);
  float accg = 0.f, accl = 0.f;
  for (int it = 0; it < 16; ++it) {
    const int row = blockIdx.x * 64 + it * 4 + w;
    const float4 rp = *(const float4*)(mfrp + (size_t)row * 68 + 64);
    float c = clean[(size_t)row * 64 + e];
    c += rp.x * sp.x + rp.y * sp.y + rp.z * sp.z + rp.w * sp.w;
    const float nv = noise[(size_t)row * 64 + e];
    const float noisy = c + nv * nsc[row];
    float v = noisy;
    int ix = e;
#pragma unroll
    for (int off = 32; off; off >>= 1) {
      const float ov = __shfl_xor(v, off);
      const int oi = __shfl_xor(ix, off);
      if (ov > v || (ov == v && oi < ix)) { v = ov; ix = oi; }
    }
    const float v1 = v;
    const int i1 = ix;
    float v2 = (e == i1) ? -FLT_MAX : noisy;
    int ix2 = e;
#pragma unroll
    for (int off = 32; off; off >>= 1) {
      const float ov = __shfl_xor(v2, off);
      const int oi = __shfl_xor(ix2, off);
      if (ov > v2 || (ov == v2 && oi < ix2)) { v2 = ov; ix2 = oi; }
    }
    const int i2 = ix2;
    if (e == 0) {
      const float texp = expf(v2 - v1);
      const float tw0 = 1.f / (1.f + texp);
      out[(size_t)row * 2 + 0] = tw0;
      out[(size_t)row * 2 + 1] = texp * tw0;
      out[32768 + (size_t)row * 2 + 0] = (float)i1;
      out[32768 + (size_t)row * 2 + 1] = (float)i2;
    }
    const float mx = wmax64(c);
    const float p = expf(c - mx);
    const float ssum = wsum64(p);
    accg += p / ssum;
    accl += (e == i1 || e == i2) ? 1.f : 0.f;
  }
  sg[w][e] = accg;
  sl[w][e] = accl;
  __syncthreads();
  if (t < 64) {
    pg[blockIdx.x * 64 + t] = sg[0][t] + sg[1][t] + sg[2][t] + sg[3][t];
    pl[blockIdx.x * 64 + t] = sl[0][t] + sl[1][t] + sl[2][t] + sl[3][t];
  }
}

// ---------- 5) aux loss ----------
__global__ void loss_kernel(const float* __restrict__ pg,
                            const float* __restrict__ pl,
                            float* __restrict__ out) {
  const int e = threadIdx.x;  // 64 threads
  float g = 0.f, l = 0.f;
  for (int b = 0; b < 256; ++b) {
    g += pg[b * 64 + e];
    l += pl[b * 64 + e];
  }
  const float prob = g * (1.f / 16384.f);
  const float ld = l * (1.f / 16384.f);
  const float load_loss = 64.f * wsum64(prob * ld);
  const float sgs = wsum64(g);
  const float mean = sgs * (1.f / 64.f);
  const float d = g - mean;
  const float var = wsum64(d * d) * (1.f / 63.f);
  if (e == 0) out[65536] = 0.01f * load_loss + 0.01f * (var / mean);
}

extern "C" void kernel_launch(void* const* d_in, const int* in_sizes, int n_in,
                              void* d_out, int out_size, void* d_ws, size_t ws_size,
                              hipStream_t stream) {
  (void)in_sizes; (void)n_in; (void)out_size; (void)ws_size;
  const float* x = (const float*)d_in[0];
  const float* noise = (const float*)d_in[1];
  const float* vol_w = (const float*)d_in[2];
  const float* vol_b = (const float*)d_in[3];
  const float* vol_g = (const float*)d_in[4];
  const float* vol_bb = (const float*)d_in[5];
  const float* trend_w = (const float*)d_in[6];
  const float* trend_b = (const float*)d_in[7];
  const float* trend_g = (const float*)d_in[8];
  const float* trend_bb = (const float*)d_in[9];
  const float* mom_w = (const float*)d_in[10];
  const float* mom_b = (const float*)d_in[11];
  const float* mom_g = (const float*)d_in[12];
  const float* mom_bb = (const float*)d_in[13];
  const float* reg_w = (const float*)d_in[14];
  const float* reg_b = (const float*)d_in[15];
  const float* reg_g = (const float*)d_in[16];
  const float* reg_bb = (const float*)d_in[17];
  const float* rc1_w = (const float*)d_in[18];
  const float* rc1_b = (const float*)d_in[19];
  const float* rc2_w = (const float*)d_in[20];
  const float* rc2_b = (const float*)d_in[21];
  const float* g1_w = (const float*)d_in[22];
  const float* g1_b = (const float*)d_in[23];
  const float* g1_g = (const float*)d_in[24];
  const float* g1_bb = (const float*)d_in[25];
  const float* g2_w = (const float*)d_in[26];
  const float* g2_b = (const float*)d_in[27];
  const float* g2_g = (const float*)d_in[28];
  const float* g2_bb = (const float*)d_in[29];
  const float* g3_w = (const float*)d_in[30];
  const float* g3_b = (const float*)d_in[31];
  const float* ns1_w = (const float*)d_in[32];
  const float* ns1_b = (const float*)d_in[33];
  const float* ns2_w = (const float*)d_in[34];
  const float* ns2_b = (const float*)d_in[35];
  const float* spec = (const float*)d_in[36];
  float* out = (float*)d_out;

  const size_t B = BROWS;
  float* ws = (float*)d_ws;
  float* mfrp = ws;                         // B*68
  float* nsc = mfrp + B * 68;               // B
  float* z1 = nsc + B;                      // B*1160 fp32
  float* giP = z1 + B * 1160;               // region: gi planes (2 x B*640 ush)
  unsigned short* gip0 = (unsigned short*)giP;
  unsigned short* gip1 = gip0 + B * 640;
  float* z2 = giP;                          // aliases gi planes (dead after G1)
  float* after = giP + B * 640;             // gi region = B*640 floats
  unsigned short* z1p0 = (unsigned short*)after;   // B*1216
  unsigned short* z1p1 = z1p0 + B * 1216;
  float* after2 = after + B * 1216;         // z1 planes = B*1216 floats
  unsigned short* w1p0 = (unsigned short*)after2;  // 1280*640
  unsigned short* w1p1 = w1p0 + 1280 * 640;
  unsigned short* w2p0 = w1p1 + 1280 * 640;        // 640*1216
  unsigned short* w2p1 = w2p0 + 640 * 1216;
  float* after3 = after2 + (2 * 1280 * 640 + 2 * 640 * 1216) / 2;
  float* cln = after3;                      // B*64
  float* pg = cln + B * 64;                 // 256*64
  float* pl = pg + 256 * 64;                // 256*64

  split_w_kernel<<<1280, 256, 0, stream>>>(g1_w, w1p0, w1p1, 1160, 580, 640);
  split_w_kernel<<<640, 256, 0, stream>>>(g2_w, w2p0, w2p1, 580, 1160, 1216);

  encoder_kernel<<<1024, 256, 0, stream>>>(
      x, vol_w, vol_b, vol_g, vol_bb, trend_w, trend_b, trend_g, trend_bb,
      mom_w, mom_b, mom_g, mom_bb, reg_w, reg_b, reg_g, reg_bb,
      rc1_w, rc1_b, rc2_w, rc2_b, ns1_w, ns1_b, ns2_w, ns2_b, mfrp, nsc);

  split_gi_kernel<<<BROWS, 256, 0, stream>>>(x, mfrp, gip0, gip1);

  // G1: [16384,640] x [1280,640]^T -> z1 (N=1160, ldc=1160)
  gemm_fp16x3_kernel<<<dim3(10, 128), 256, 0, stream>>>(
      gip0, gip1, w1p0, w1p1, g1_b, z1, 1160, 640, 1160);
  ln_gelu_split_kernel<<<BROWS, 256, 0, stream>>>(z1, g1_g, g1_bb, z1p0, z1p1);

  // G2: [16384,1216] x [640,1216]^T -> z2 (N=580, ldc=580)
  gemm_fp16x3_kernel<<<dim3(5, 128), 256, 0, stream>>>(
      z1p0, z1p1, w2p0, w2p1, g2_b, z2, 580, 1216, 580);
  ln_gelu_kernel<<<BROWS, 256, 0, stream>>>(z2, g2_g, g2_bb, 580);

  // G3: [16384,580] x [64,580]^T -> clean (fp32)
  gemm128_kernel<false><<<dim3(128, 1), 256, 0, stream>>>(
      z2, nullptr, g3_w, g3_b, cln, BROWS, 64, 580);

  final_kernel<<<256, 256, 0, stream>>>(cln, mfrp, nsc, noise, spec, out, pg, pl);
  loss_kernel<<<1, 64, 0, stream>>>(pg, pl, out);
}

// Round 5
// 498.224 us; speedup vs baseline: 2.2791x; 1.2220x over previous
//
#include <hip/hip_runtime.h>
#include <hip/hip_fp16.h>
#include <cfloat>

#define BROWS 16384

typedef float f32x4 __attribute__((ext_vector_type(4)));
typedef _Float16 f16x8 __attribute__((ext_vector_type(8)));

// ---------- wave helpers ----------
__device__ __forceinline__ float wsum64(float v) {
#pragma unroll
  for (int off = 32; off; off >>= 1) v += __shfl_xor(v, off);
  return v;
}
__device__ __forceinline__ float wmax64(float v) {
#pragma unroll
  for (int off = 32; off; off >>= 1) v = fmaxf(v, __shfl_xor(v, off));
  return v;
}
__device__ __forceinline__ float gsum16(float v) {
#pragma unroll
  for (int off = 1; off < 16; off <<= 1) v += __shfl_xor(v, off);
  return v;
}

// fp16 2-limb split: v ~= h0 + 2^-11 * h1, residual <= 2^-24 |v|
__device__ __forceinline__ void split2(float v, unsigned short& o0, unsigned short& o1) {
  const _Float16 h0 = (_Float16)v;
  const float r = (v - (float)h0) * 2048.0f;
  const _Float16 h1 = (_Float16)r;
  o0 = __builtin_bit_cast(unsigned short, h0);
  o1 = __builtin_bit_cast(unsigned short, h1);
}

// async global -> LDS, 16B per lane, dest = wave-uniform base + lane*16
__device__ __forceinline__ void gll16(const unsigned short* g, unsigned short* l) {
  __builtin_amdgcn_global_load_lds(
      (const __attribute__((address_space(1))) unsigned int*)g,
      (__attribute__((address_space(3))) unsigned int*)l, 16, 0, 0);
}

// ---------- 1) market encoder + router + noise-scale ----------
__global__ __launch_bounds__(256) void encoder_kernel(
    const float* __restrict__ x,
    const float* __restrict__ vol_w, const float* __restrict__ vol_b,
    const float* __restrict__ vol_g, const float* __restrict__ vol_bb,
    const float* __restrict__ trend_w, const float* __restrict__ trend_b,
    const float* __restrict__ trend_g, const float* __restrict__ trend_bb,
    const float* __restrict__ mom_w, const float* __restrict__ mom_b,
    const float* __restrict__ mom_g, const float* __restrict__ mom_bb,
    const float* __restrict__ reg_w, const float* __restrict__ reg_b,
    const float* __restrict__ reg_g, const float* __restrict__ reg_bb,
    const float* __restrict__ rc1_w, const float* __restrict__ rc1_b,
    const float* __restrict__ rc2_w, const float* __restrict__ rc2_b,
    const float* __restrict__ ns1_w, const float* __restrict__ ns1_b,
    const float* __restrict__ ns2_w, const float* __restrict__ ns2_b,
    float* __restrict__ mfrp, float* __restrict__ nsc) {
  const int t = threadIdx.x;
  const int w = t >> 6;
  const int e = t & 63;
  const int br = e >> 4;
  const int rowbase = blockIdx.x * 16 + w * 4;
  const int rb = __builtin_amdgcn_readfirstlane(rowbase);

  const float* wsel = (br == 0) ? vol_w : (br == 1) ? trend_w : (br == 2) ? mom_w : reg_w;
  const float* bsel = (br == 0) ? vol_b : (br == 1) ? trend_b : (br == 2) ? mom_b : reg_b;
  const float* gsel = (br == 0) ? vol_g : (br == 1) ? trend_g : (br == 2) ? mom_g : reg_g;
  const float* bbsel = (br == 0) ? vol_bb : (br == 1) ? trend_bb : (br == 2) ? mom_bb : reg_bb;
  const float* wrow = wsel + (size_t)(e & 15) * 512;

  float acc0 = 0.f, acc1 = 0.f, acc2 = 0.f, acc3 = 0.f;
  const float* xr = x + (size_t)rb * 512;
  for (int k = 0; k < 512; k += 4) {
    const float4 wv = *(const float4*)(wrow + k);
    const float4 x0 = *(const float4*)(xr + k);
    const float4 x1 = *(const float4*)(xr + 512 + k);
    const float4 x2 = *(const float4*)(xr + 1024 + k);
    const float4 x3 = *(const float4*)(xr + 1536 + k);
    acc0 += wv.x * x0.x + wv.y * x0.y + wv.z * x0.z + wv.w * x0.w;
    acc1 += wv.x * x1.x + wv.y * x1.y + wv.z * x1.z + wv.w * x1.w;
    acc2 += wv.x * x2.x + wv.y * x2.y + wv.z * x2.z + wv.w * x2.w;
    acc3 += wv.x * x3.x + wv.y * x3.y + wv.z * x3.z + wv.w * x3.w;
  }
  const float bias = bsel[e & 15];
  const float gv = gsel[e & 15];
  const float bbv = bbsel[e & 15];

  __shared__ float smf[4][4][64];
  __shared__ float shid[4][4][32];
  __shared__ float srp[4][4][4];

  float vr[4] = {acc0 + bias, acc1 + bias, acc2 + bias, acc3 + bias};
#pragma unroll
  for (int r = 0; r < 4; ++r) {
    const float v = fmaxf(vr[r], 0.f);
    const float mu = gsum16(v) * (1.f / 16.f);
    const float d = v - mu;
    const float var = gsum16(d * d) * (1.f / 16.f);
    const float mfv = d * (1.f / sqrtf(var + 1e-5f)) * gv + bbv;
    mfrp[(size_t)(rowbase + r) * 68 + e] = mfv;
    smf[w][r][e] = mfv;
  }
  __syncthreads();
  if (e < 32) {
#pragma unroll
    for (int r = 0; r < 4; ++r) {
      float h = rc1_b[e];
#pragma unroll 8
      for (int j = 0; j < 64; ++j) h += rc1_w[e * 64 + j] * smf[w][r][j];
      shid[w][r][e] = fmaxf(h, 0.f);
    }
  }
  __syncthreads();
  if (e < 16) {
    const int r = e >> 2, l = e & 3;
    float z = rc2_b[l];
#pragma unroll 8
    for (int j = 0; j < 32; ++j) z += rc2_w[l * 32 + j] * shid[w][r][j];
    float mx = z;
    mx = fmaxf(mx, __shfl_xor(mx, 1));
    mx = fmaxf(mx, __shfl_xor(mx, 2));
    const float ex = expf(z - mx);
    float s = ex;
    s += __shfl_xor(s, 1);
    s += __shfl_xor(s, 2);
    const float rp = ex / s;
    srp[w][r][l] = rp;
    mfrp[(size_t)(rowbase + r) * 68 + 64 + l] = rp;
  }
  __syncthreads();
  if (e < 4) {
    const int r = e;
    const float rp0 = srp[w][r][0], rp1 = srp[w][r][1], rp2 = srp[w][r][2], rp3 = srp[w][r][3];
    float z = ns2_b[0];
#pragma unroll
    for (int i = 0; i < 16; ++i) {
      float h = ns1_b[i] + ns1_w[i * 4 + 0] * rp0 + ns1_w[i * 4 + 1] * rp1 +
                ns1_w[i * 4 + 2] * rp2 + ns1_w[i * 4 + 3] * rp3;
      z += ns2_w[i] * fmaxf(h, 0.f);
    }
    nsc[rowbase + r] = 1.f / (1.f + expf(-z));
  }
}

// ---------- splits: fp32 -> 2 fp16 limb planes (zero-padded) ----------
__global__ __launch_bounds__(256) void split_gi_kernel(
    const float* __restrict__ x, const float* __restrict__ mfrp,
    unsigned short* __restrict__ p0, unsigned short* __restrict__ p1) {
  const int row = blockIdx.x;
  const int Kp = 640;
#pragma unroll
  for (int c = 0; c < 3; ++c) {
    const int i = threadIdx.x + c * 256;
    if (i < Kp) {
      float v = 0.f;
      if (i < 512) v = x[(size_t)row * 512 + i];
      else if (i < 580) v = mfrp[(size_t)row * 68 + (i - 512)];
      unsigned short h0, h1;
      split2(v, h0, h1);
      p0[(size_t)row * Kp + i] = h0;
      p1[(size_t)row * Kp + i] = h1;
    }
  }
}

__global__ __launch_bounds__(256) void split_w_kernel(
    const float* __restrict__ W, unsigned short* __restrict__ p0,
    unsigned short* __restrict__ p1, int N, int K, int Kp) {
  const int n = blockIdx.x;  // over padded rows
  for (int i = threadIdx.x; i < Kp; i += 256) {
    const float v = (n < N && i < K) ? W[(size_t)n * K + i] : 0.f;
    unsigned short h0, h1;
    split2(v, h0, h1);
    p0[(size_t)n * Kp + i] = h0;
    p1[(size_t)n * Kp + i] = h1;
  }
}

// ---------- 2) merged fp16x3 MFMA GEMM, 2-phase dbuf, XOR-swizzled LDS ----------
// C = A0B0 + 2^-11*(A1B0 + A0B1) + bias; dropped A1B1 ~2^-24 rel.
// Tile 128x128, BK=32, 4 waves (2x2 of 64x64), 16x16x32 f16 MFMA.
// LDS [128][32] f16 per plane (64B rows, 4x16B chunks); swizzle:
// physical chunk = logical chunk ^ (row&3), realized by pre-swizzling
// the global SOURCE of global_load_lds (linear dest) and XORing reads.
__global__ __launch_bounds__(256, 2) void gemm_fp16x3_v2(
    const unsigned short* __restrict__ Ap0, const unsigned short* __restrict__ Ap1,
    const unsigned short* __restrict__ Bp0, const unsigned short* __restrict__ Bp1,
    const float* __restrict__ bias, float* __restrict__ C,
    int N, int Kp, int ldc, int nbx) {
  __shared__ __align__(16) unsigned short A0s[2][128][32];
  __shared__ __align__(16) unsigned short A1s[2][128][32];
  __shared__ __align__(16) unsigned short B0s[2][128][32];
  __shared__ __align__(16) unsigned short B1s[2][128][32];
  const int t = threadIdx.x;
  // bijective XCD swizzle (gridDim.x % 8 == 0 for all our launches)
  const int wg = (blockIdx.x & 7) * ((int)gridDim.x >> 3) + (blockIdx.x >> 3);
  const int bx = wg % nbx, by = wg / nbx;
  const int m0 = by * 128, n0 = bx * 128;
  const int w = t >> 6, l = t & 63;
  const int lr = l & 15, lc = l >> 4;
  const int wm = (w >> 1) * 64, wn = (w & 1) * 64;
  // staging geometry: per call, 256 threads cover 64 rows x 64B
  const int wrow = w * 16;                      // wave-uniform LDS row base
  const int lrow = l >> 2;                      // 0..15: lane row within wave group
  const int csrc = ((l & 3) ^ (lrow & 3)) * 8;  // pre-swizzled source chunk (elems)

  f32x4 accM[4][4], accL[4][4];
#pragma unroll
  for (int i = 0; i < 4; ++i)
#pragma unroll
    for (int j = 0; j < 4; ++j) {
      accM[i][j] = (f32x4){0.f, 0.f, 0.f, 0.f};
      accL[i][j] = (f32x4){0.f, 0.f, 0.f, 0.f};
    }

  const int KT = Kp >> 5;

  auto stage = [&](int kt, int bb) {
    const int kb = kt * 32 + csrc;
#pragma unroll
    for (int c = 0; c < 2; ++c) {
      const int rb = c * 64 + wrow;   // wave-uniform
      const int gr = rb + lrow;       // per-lane global row
      gll16(Ap0 + (size_t)(m0 + gr) * Kp + kb, &A0s[bb][rb][0]);
      gll16(Ap1 + (size_t)(m0 + gr) * Kp + kb, &A1s[bb][rb][0]);
      gll16(Bp0 + (size_t)(n0 + gr) * Kp + kb, &B0s[bb][rb][0]);
      gll16(Bp1 + (size_t)(n0 + gr) * Kp + kb, &B1s[bb][rb][0]);
    }
  };

  stage(0, 0);
  __syncthreads();  // drains vmcnt(0) before barrier (compiler semantics)
  int cur = 0;
  for (int kt = 0; kt < KT; ++kt) {
    if (kt + 1 < KT) stage(kt + 1, cur ^ 1);  // prefetch next tile (other buffer)
    // frag reads: logical chunk lc at row -> physical chunk lc ^ (row&3)
    f16x8 a0[4], a1[4], b0[4], b1[4];
#pragma unroll
    for (int i = 0; i < 4; ++i) {
      const int ar = wm + i * 16 + lr;
      const int sw = ((lc ^ (ar & 3)) << 4);
      a0[i] = *(const f16x8*)((const char*)&A0s[cur][ar][0] + sw);
      a1[i] = *(const f16x8*)((const char*)&A1s[cur][ar][0] + sw);
    }
#pragma unroll
    for (int j = 0; j < 4; ++j) {
      const int brj = wn + j * 16 + lr;
      const int sw = ((lc ^ (brj & 3)) << 4);
      b0[j] = *(const f16x8*)((const char*)&B0s[cur][brj][0] + sw);
      b1[j] = *(const f16x8*)((const char*)&B1s[cur][brj][0] + sw);
    }
#pragma unroll
    for (int i = 0; i < 4; ++i)
#pragma unroll
      for (int j = 0; j < 4; ++j) {
        accL[i][j] = __builtin_amdgcn_mfma_f32_16x16x32_f16(a1[i], b0[j], accL[i][j], 0, 0, 0);
        accL[i][j] = __builtin_amdgcn_mfma_f32_16x16x32_f16(a0[i], b1[j], accL[i][j], 0, 0, 0);
        accM[i][j] = __builtin_amdgcn_mfma_f32_16x16x32_f16(a0[i], b0[j], accM[i][j], 0, 0, 0);
      }
    __syncthreads();  // next tile staged + everyone done reading cur
    cur ^= 1;
  }
  // epilogue: D layout col(lane&15)=n, row((lane>>4)*4+reg)=m  [R2/R3-verified]
#pragma unroll
  for (int j = 0; j < 4; ++j) {
    const int n = n0 + wn + j * 16 + lr;
    if (n < N) {
      const float bz = bias[n];
#pragma unroll
      for (int i = 0; i < 4; ++i) {
        const int mb = m0 + wm + i * 16 + lc * 4;
#pragma unroll
        for (int r = 0; r < 4; ++r)
          C[(size_t)(mb + r) * (size_t)ldc + n] =
              accM[i][j][r] + 0.00048828125f * accL[i][j][r] + bz;
      }
    }
  }
}

// ---------- 2b) fp32 tiled GEMM (G3, N=64 last layer) ----------
template <bool GATHER>
__global__ __launch_bounds__(256, 4) void gemm128_kernel(
    const float* __restrict__ A, const float* __restrict__ mfrp,
    const float* __restrict__ W, const float* __restrict__ bias,
    float* __restrict__ C, int M, int N, int K) {
  __shared__ float As[16][132];
  __shared__ float Bs[16][132];
  const int t = threadIdx.x;
  const int m0 = blockIdx.x * 128;
  const int n0 = blockIdx.y * 128;
  const int tx = t & 15, ty = t >> 4;
  const int srow = t >> 1;
  const int skc = (t & 1) * 8;

  float acc[2][2][4][4] = {};
  const int nk = (K + 15) >> 4;
  const int arow = m0 + srow;
  const int brow = n0 + srow;
  const bool bvalid = brow < N;

  for (int kt = 0; kt < nk; ++kt) {
    const int k0 = kt * 16;
    float4 av[2], bv[2];
#pragma unroll
    for (int c = 0; c < 2; ++c) {
      const int k = k0 + skc + c * 4;
      float4 va = {0.f, 0.f, 0.f, 0.f};
      if (GATHER) {
        if (k < 512) va = *(const float4*)(A + (size_t)arow * 512 + k);
        else if (k < 580) va = *(const float4*)(mfrp + (size_t)arow * 68 + (k - 512));
      } else {
        if (k < K) va = *(const float4*)(A + (size_t)arow * K + k);
      }
      av[c] = va;
      float4 vb = {0.f, 0.f, 0.f, 0.f};
      if (bvalid && k < K) vb = *(const float4*)(W + (size_t)brow * K + k);
      bv[c] = vb;
    }
    __syncthreads();
#pragma unroll
    for (int c = 0; c < 2; ++c) {
      As[skc + c * 4 + 0][srow] = av[c].x;
      As[skc + c * 4 + 1][srow] = av[c].y;
      As[skc + c * 4 + 2][srow] = av[c].z;
      As[skc + c * 4 + 3][srow] = av[c].w;
      Bs[skc + c * 4 + 0][srow] = bv[c].x;
      Bs[skc + c * 4 + 1][srow] = bv[c].y;
      Bs[skc + c * 4 + 2][srow] = bv[c].z;
      Bs[skc + c * 4 + 3][srow] = bv[c].w;
    }
    __syncthreads();
#pragma unroll
    for (int k = 0; k < 16; ++k) {
      const float4 a0 = *(const float4*)&As[k][ty << 2];
      const float4 a1 = *(const float4*)&As[k][(ty << 2) + 64];
      const float4 b0 = *(const float4*)&Bs[k][tx << 2];
      const float4 b1 = *(const float4*)&Bs[k][(tx << 2) + 64];
      const float aa[2][4] = {{a0.x, a0.y, a0.z, a0.w}, {a1.x, a1.y, a1.z, a1.w}};
      const float bb[2][4] = {{b0.x, b0.y, b0.z, b0.w}, {b1.x, b1.y, b1.z, b1.w}};
#pragma unroll
      for (int i2 = 0; i2 < 2; ++i2)
#pragma unroll
        for (int i = 0; i < 4; ++i)
#pragma unroll
          for (int j2 = 0; j2 < 2; ++j2)
#pragma unroll
            for (int j = 0; j < 4; ++j)
              acc[i2][j2][i][j] = fmaf(aa[i2][i], bb[j2][j], acc[i2][j2][i][j]);
    }
  }
#pragma unroll
  for (int j2 = 0; j2 < 2; ++j2) {
    const int n = n0 + j2 * 64 + (tx << 2);
    if (n < N) {
      const float4 bz = *(const float4*)(bias + n);
#pragma unroll
      for (int i2 = 0; i2 < 2; ++i2)
#pragma unroll
        for (int i = 0; i < 4; ++i) {
          const int m = m0 + i2 * 64 + (ty << 2) + i;
          float4 o;
          o.x = acc[i2][j2][i][0] + bz.x;
          o.y = acc[i2][j2][i][1] + bz.y;
          o.z = acc[i2][j2][i][2] + bz.z;
          o.w = acc[i2][j2][i][3] + bz.w;
          *(float4*)(C + (size_t)m * N + n) = o;
        }
    }
  }
}

// ---------- 3a) row LayerNorm + exact GELU -> fp16 limb planes (z1) ----------
__global__ __launch_bounds__(256) void ln_gelu_split_kernel(
    const float* __restrict__ Z, const float* __restrict__ gamma,
    const float* __restrict__ beta, unsigned short* __restrict__ p0,
    unsigned short* __restrict__ p1) {
  const int N = 1160, Kp = 1216;
  __shared__ float sred[4];
  const int t = threadIdx.x;
  const float* zr = Z + (size_t)blockIdx.x * N;
  float vals[5];
  float s = 0.f;
#pragma unroll
  for (int c = 0; c < 5; ++c) {
    const int i = t + c * 256;
    const float v = (i < N) ? zr[i] : 0.f;
    vals[c] = v;
    s += v;
  }
  s = wsum64(s);
  if ((t & 63) == 0) sred[t >> 6] = s;
  __syncthreads();
  const float mu = (sred[0] + sred[1] + sred[2] + sred[3]) / (float)N;
  __syncthreads();
  float q = 0.f;
#pragma unroll
  for (int c = 0; c < 5; ++c) {
    const int i = t + c * 256;
    if (i < N) {
      const float d = vals[c] - mu;
      q += d * d;
    }
  }
  q = wsum64(q);
  if ((t & 63) == 0) sred[t >> 6] = q;
  __syncthreads();
  const float var = (sred[0] + sred[1] + sred[2] + sred[3]) / (float)N;
  const float rstd = 1.f / sqrtf(var + 1e-5f);
#pragma unroll
  for (int c = 0; c < 5; ++c) {
    const int i = t + c * 256;
    if (i < Kp) {
      float g = 0.f;
      if (i < N) {
        const float y = (vals[c] - mu) * rstd * gamma[i] + beta[i];
        g = 0.5f * y * (1.f + erff(y * 0.70710678118654752f));
      }
      unsigned short h0, h1;
      split2(g, h0, h1);
      p0[(size_t)blockIdx.x * Kp + i] = h0;
      p1[(size_t)blockIdx.x * Kp + i] = h1;
    }
  }
}

// ---------- 3b) in-place row LayerNorm + exact GELU (z2) ----------
__global__ __launch_bounds__(256) void ln_gelu_kernel(
    float* __restrict__ Z, const float* __restrict__ gamma,
    const float* __restrict__ beta, const int N) {
  __shared__ float sred[4];
  const int t = threadIdx.x;
  float* zr = Z + (size_t)blockIdx.x * N;
  float vals[5];
  float s = 0.f;
#pragma unroll
  for (int c = 0; c < 5; ++c) {
    const int i = t + c * 256;
    const float v = (i < N) ? zr[i] : 0.f;
    vals[c] = v;
    s += v;
  }
  s = wsum64(s);
  if ((t & 63) == 0) sred[t >> 6] = s;
  __syncthreads();
  const float mu = (sred[0] + sred[1] + sred[2] + sred[3]) / (float)N;
  __syncthreads();
  float q = 0.f;
#pragma unroll
  for (int c = 0; c < 5; ++c) {
    const int i = t + c * 256;
    if (i < N) {
      const float d = vals[c] - mu;
      q += d * d;
    }
  }
  q = wsum64(q);
  if ((t & 63) == 0) sred[t >> 6] = q;
  __syncthreads();
  const float var = (sred[0] + sred[1] + sred[2] + sred[3]) / (float)N;
  const float rstd = 1.f / sqrtf(var + 1e-5f);
#pragma unroll
  for (int c = 0; c < 5; ++c) {
    const int i = t + c * 256;
    if (i < N) {
      const float y = (vals[c] - mu) * rstd * gamma[i] + beta[i];
      zr[i] = 0.5f * y * (1.f + erff(y * 0.70710678118654752f));
    }
  }
}

// ---------- 4) final: +rp*spec^T, noise, top-2, gates, partials ----------
__global__ __launch_bounds__(256) void final_kernel(
    const float* __restrict__ clean, const float* __restrict__ mfrp,
    const float* __restrict__ nsc, const float* __restrict__ noise,
    const float* __restrict__ spec, float* __restrict__ out,
    float* __restrict__ pg, float* __restrict__ pl) {
  const int t = threadIdx.x;
  const int w = t >> 6;
  const int e = t & 63;
  __shared__ float sg[4][64];
  __shared__ float sl[4][64];
  const float4 sp = *(const float4*)(spec + e * 4);
  float accg = 0.f, accl = 0.f;
  for (int it = 0; it < 16; ++it) {
    const int row = blockIdx.x * 64 + it * 4 + w;
    const float4 rp = *(const float4*)(mfrp + (size_t)row * 68 + 64);
    float c = clean[(size_t)row * 64 + e];
    c += rp.x * sp.x + rp.y * sp.y + rp.z * sp.z + rp.w * sp.w;
    const float nv = noise[(size_t)row * 64 + e];
    const float noisy = c + nv * nsc[row];
    float v = noisy;
    int ix = e;
#pragma unroll
    for (int off = 32; off; off >>= 1) {
      const float ov = __shfl_xor(v, off);
      const int oi = __shfl_xor(ix, off);
      if (ov > v || (ov == v && oi < ix)) { v = ov; ix = oi; }
    }
    const float v1 = v;
    const int i1 = ix;
    float v2 = (e == i1) ? -FLT_MAX : noisy;
    int ix2 = e;
#pragma unroll
    for (int off = 32; off; off >>= 1) {
      const float ov = __shfl_xor(v2, off);
      const int oi = __shfl_xor(ix2, off);
      if (ov > v2 || (ov == v2 && oi < ix2)) { v2 = ov; ix2 = oi; }
    }
    const int i2 = ix2;
    if (e == 0) {
      const float texp = expf(v2 - v1);
      const float tw0 = 1.f / (1.f + texp);
      out[(size_t)row * 2 + 0] = tw0;
      out[(size_t)row * 2 + 1] = texp * tw0;
      out[32768 + (size_t)row * 2 + 0] = (float)i1;
      out[32768 + (size_t)row * 2 + 1] = (float)i2;
    }
    const float mx = wmax64(c);
    const float p = expf(c - mx);
    const float ssum = wsum64(p);
    accg += p / ssum;
    accl += (e == i1 || e == i2) ? 1.f : 0.f;
  }
  sg[w][e] = accg;
  sl[w][e] = accl;
  __syncthreads();
  if (t < 64) {
    pg[blockIdx.x * 64 + t] = sg[0][t] + sg[1][t] + sg[2][t] + sg[3][t];
    pl[blockIdx.x * 64 + t] = sl[0][t] + sl[1][t] + sl[2][t] + sl[3][t];
  }
}

// ---------- 5) aux loss ----------
__global__ void loss_kernel(const float* __restrict__ pg,
                            const float* __restrict__ pl,
                            float* __restrict__ out) {
  const int e = threadIdx.x;  // 64 threads
  float g = 0.f, l = 0.f;
  for (int b = 0; b < 256; ++b) {
    g += pg[b * 64 + e];
    l += pl[b * 64 + e];
  }
  const float prob = g * (1.f / 16384.f);
  const float ld = l * (1.f / 16384.f);
  const float load_loss = 64.f * wsum64(prob * ld);
  const float sgs = wsum64(g);
  const float mean = sgs * (1.f / 64.f);
  const float d = g - mean;
  const float var = wsum64(d * d) * (1.f / 63.f);
  if (e == 0) out[65536] = 0.01f * load_loss + 0.01f * (var / mean);
}

extern "C" void kernel_launch(void* const* d_in, const int* in_sizes, int n_in,
                              void* d_out, int out_size, void* d_ws, size_t ws_size,
                              hipStream_t stream) {
  (void)in_sizes; (void)n_in; (void)out_size; (void)ws_size;
  const float* x = (const float*)d_in[0];
  const float* noise = (const float*)d_in[1];
  const float* vol_w = (const float*)d_in[2];
  const float* vol_b = (const float*)d_in[3];
  const float* vol_g = (const float*)d_in[4];
  const float* vol_bb = (const float*)d_in[5];
  const float* trend_w = (const float*)d_in[6];
  const float* trend_b = (const float*)d_in[7];
  const float* trend_g = (const float*)d_in[8];
  const float* trend_bb = (const float*)d_in[9];
  const float* mom_w = (const float*)d_in[10];
  const float* mom_b = (const float*)d_in[11];
  const float* mom_g = (const float*)d_in[12];
  const float* mom_bb = (const float*)d_in[13];
  const float* reg_w = (const float*)d_in[14];
  const float* reg_b = (const float*)d_in[15];
  const float* reg_g = (const float*)d_in[16];
  const float* reg_bb = (const float*)d_in[17];
  const float* rc1_w = (const float*)d_in[18];
  const float* rc1_b = (const float*)d_in[19];
  const float* rc2_w = (const float*)d_in[20];
  const float* rc2_b = (const float*)d_in[21];
  const float* g1_w = (const float*)d_in[22];
  const float* g1_b = (const float*)d_in[23];
  const float* g1_g = (const float*)d_in[24];
  const float* g1_bb = (const float*)d_in[25];
  const float* g2_w = (const float*)d_in[26];
  const float* g2_b = (const float*)d_in[27];
  const float* g2_g = (const float*)d_in[28];
  const float* g2_bb = (const float*)d_in[29];
  const float* g3_w = (const float*)d_in[30];
  const float* g3_b = (const float*)d_in[31];
  const float* ns1_w = (const float*)d_in[32];
  const float* ns1_b = (const float*)d_in[33];
  const float* ns2_w = (const float*)d_in[34];
  const float* ns2_b = (const float*)d_in[35];
  const float* spec = (const float*)d_in[36];
  float* out = (float*)d_out;

  const size_t B = BROWS;
  float* ws = (float*)d_ws;
  float* mfrp = ws;                         // B*68
  float* nsc = mfrp + B * 68;               // B
  float* z1 = nsc + B;                      // B*1160 fp32
  float* giP = z1 + B * 1160;               // region: gi planes (2 x B*640 ush)
  unsigned short* gip0 = (unsigned short*)giP;
  unsigned short* gip1 = gip0 + B * 640;
  float* z2 = giP;                          // aliases gi planes (dead after G1)
  float* after = giP + B * 640;             // gi region = B*640 floats
  unsigned short* z1p0 = (unsigned short*)after;   // B*1216
  unsigned short* z1p1 = z1p0 + B * 1216;
  float* after2 = after + B * 1216;         // z1 planes = B*1216 floats
  unsigned short* w1p0 = (unsigned short*)after2;  // 1280*640
  unsigned short* w1p1 = w1p0 + 1280 * 640;
  unsigned short* w2p0 = w1p1 + 1280 * 640;        // 640*1216
  unsigned short* w2p1 = w2p0 + 640 * 1216;
  float* after3 = after2 + (2 * 1280 * 640 + 2 * 640 * 1216) / 2;
  float* cln = after3;                      // B*64
  float* pg = cln + B * 64;                 // 256*64
  float* pl = pg + 256 * 64;                // 256*64

  split_w_kernel<<<1280, 256, 0, stream>>>(g1_w, w1p0, w1p1, 1160, 580, 640);
  split_w_kernel<<<640, 256, 0, stream>>>(g2_w, w2p0, w2p1, 580, 1160, 1216);

  encoder_kernel<<<1024, 256, 0, stream>>>(
      x, vol_w, vol_b, vol_g, vol_bb, trend_w, trend_b, trend_g, trend_bb,
      mom_w, mom_b, mom_g, mom_bb, reg_w, reg_b, reg_g, reg_bb,
      rc1_w, rc1_b, rc2_w, rc2_b, ns1_w, ns1_b, ns2_w, ns2_b, mfrp, nsc);

  split_gi_kernel<<<BROWS, 256, 0, stream>>>(x, mfrp, gip0, gip1);

  // G1: [16384,640] x [1280,640]^T -> z1 (N=1160, ldc=1160); grid 1280 = 8*160
  gemm_fp16x3_v2<<<1280, 256, 0, stream>>>(
      gip0, gip1, w1p0, w1p1, g1_b, z1, 1160, 640, 1160, 10);
  ln_gelu_split_kernel<<<BROWS, 256, 0, stream>>>(z1, g1_g, g1_bb, z1p0, z1p1);

  // G2: [16384,1216] x [640,1216]^T -> z2 (N=580, ldc=580); grid 640 = 8*80
  gemm_fp16x3_v2<<<640, 256, 0, stream>>>(
      z1p0, z1p1, w2p0, w2p1, g2_b, z2, 580, 1216, 580, 5);
  ln_gelu_kernel<<<BROWS, 256, 0, stream>>>(z2, g2_g, g2_bb, 580);

  // G3: [16384,580] x [64,580]^T -> clean (fp32)
  gemm128_kernel<false><<<dim3(128, 1), 256, 0, stream>>>(
      z2, nullptr, g3_w, g3_b, cln, BROWS, 64, 580);

  final_kernel<<<256, 256, 0, stream>>>(cln, mfrp, nsc, noise, spec, out, pg, pl);
  loss_kernel<<<1, 64, 0, stream>>>(pg, pl, out);
}

// Round 6
// 474.451 us; speedup vs baseline: 2.3933x; 1.0501x over previous
//
#include <hip/hip_runtime.h>
#include <hip/hip_fp16.h>
#include <cfloat>

#define BROWS 16384

typedef float f32x4 __attribute__((ext_vector_type(4)));
typedef _Float16 f16x8 __attribute__((ext_vector_type(8)));

// ---------- wave helpers ----------
__device__ __forceinline__ float wsum64(float v) {
#pragma unroll
  for (int off = 32; off; off >>= 1) v += __shfl_xor(v, off);
  return v;
}
__device__ __forceinline__ float wmax64(float v) {
#pragma unroll
  for (int off = 32; off; off >>= 1) v = fmaxf(v, __shfl_xor(v, off));
  return v;
}
__device__ __forceinline__ float gsum16(float v) {
#pragma unroll
  for (int off = 1; off < 16; off <<= 1) v += __shfl_xor(v, off);
  return v;
}

// fp16 2-limb split: v ~= h0 + 2^-11 * h1, residual <= 2^-24 |v|
__device__ __forceinline__ void split2(float v, unsigned short& o0, unsigned short& o1) {
  const _Float16 h0 = (_Float16)v;
  const float r = (v - (float)h0) * 2048.0f;
  const _Float16 h1 = (_Float16)r;
  o0 = __builtin_bit_cast(unsigned short, h0);
  o1 = __builtin_bit_cast(unsigned short, h1);
}

// async global -> LDS, 16B per lane, dest = wave-uniform base + lane*16
__device__ __forceinline__ void gll16(const unsigned short* g, unsigned short* l) {
  __builtin_amdgcn_global_load_lds(
      (const __attribute__((address_space(1))) unsigned int*)g,
      (__attribute__((address_space(3))) unsigned int*)l, 16, 0, 0);
}

// Combined swizzled plane format for a matrix split into 2 fp16 limbs:
//   buffer[(r*KT + kt)*64 + p*8 + s], p = physical 16B chunk 0..7.
//   logical chunk c(0..3)=limb0 k=kt*32+c*8+s; c(4..7)=limb1 (k-offset (c-4)*8+s).
//   physical p = c ^ (r & 7)  -> conflict-free ds_read_b128 in the GEMM.

// ---------- 1) market encoder + router + noise-scale ----------
__global__ __launch_bounds__(256) void encoder_kernel(
    const float* __restrict__ x,
    const float* __restrict__ vol_w, const float* __restrict__ vol_b,
    const float* __restrict__ vol_g, const float* __restrict__ vol_bb,
    const float* __restrict__ trend_w, const float* __restrict__ trend_b,
    const float* __restrict__ trend_g, const float* __restrict__ trend_bb,
    const float* __restrict__ mom_w, const float* __restrict__ mom_b,
    const float* __restrict__ mom_g, const float* __restrict__ mom_bb,
    const float* __restrict__ reg_w, const float* __restrict__ reg_b,
    const float* __restrict__ reg_g, const float* __restrict__ reg_bb,
    const float* __restrict__ rc1_w, const float* __restrict__ rc1_b,
    const float* __restrict__ rc2_w, const float* __restrict__ rc2_b,
    const float* __restrict__ ns1_w, const float* __restrict__ ns1_b,
    const float* __restrict__ ns2_w, const float* __restrict__ ns2_b,
    float* __restrict__ mfrp, float* __restrict__ nsc) {
  const int t = threadIdx.x;
  const int w = t >> 6;
  const int e = t & 63;
  const int br = e >> 4;
  const int rowbase = blockIdx.x * 16 + w * 4;
  const int rb = __builtin_amdgcn_readfirstlane(rowbase);

  const float* wsel = (br == 0) ? vol_w : (br == 1) ? trend_w : (br == 2) ? mom_w : reg_w;
  const float* bsel = (br == 0) ? vol_b : (br == 1) ? trend_b : (br == 2) ? mom_b : reg_b;
  const float* gsel = (br == 0) ? vol_g : (br == 1) ? trend_g : (br == 2) ? mom_g : reg_g;
  const float* bbsel = (br == 0) ? vol_bb : (br == 1) ? trend_bb : (br == 2) ? mom_bb : reg_bb;
  const float* wrow = wsel + (size_t)(e & 15) * 512;

  float acc0 = 0.f, acc1 = 0.f, acc2 = 0.f, acc3 = 0.f;
  const float* xr = x + (size_t)rb * 512;
  for (int k = 0; k < 512; k += 4) {
    const float4 wv = *(const float4*)(wrow + k);
    const float4 x0 = *(const float4*)(xr + k);
    const float4 x1 = *(const float4*)(xr + 512 + k);
    const float4 x2 = *(const float4*)(xr + 1024 + k);
    const float4 x3 = *(const float4*)(xr + 1536 + k);
    acc0 += wv.x * x0.x + wv.y * x0.y + wv.z * x0.z + wv.w * x0.w;
    acc1 += wv.x * x1.x + wv.y * x1.y + wv.z * x1.z + wv.w * x1.w;
    acc2 += wv.x * x2.x + wv.y * x2.y + wv.z * x2.z + wv.w * x2.w;
    acc3 += wv.x * x3.x + wv.y * x3.y + wv.z * x3.z + wv.w * x3.w;
  }
  const float bias = bsel[e & 15];
  const float gv = gsel[e & 15];
  const float bbv = bbsel[e & 15];

  __shared__ float smf[4][4][64];
  __shared__ float shid[4][4][32];
  __shared__ float srp[4][4][4];

  float vr[4] = {acc0 + bias, acc1 + bias, acc2 + bias, acc3 + bias};
#pragma unroll
  for (int r = 0; r < 4; ++r) {
    const float v = fmaxf(vr[r], 0.f);
    const float mu = gsum16(v) * (1.f / 16.f);
    const float d = v - mu;
    const float var = gsum16(d * d) * (1.f / 16.f);
    const float mfv = d * (1.f / sqrtf(var + 1e-5f)) * gv + bbv;
    mfrp[(size_t)(rowbase + r) * 68 + e] = mfv;
    smf[w][r][e] = mfv;
  }
  __syncthreads();
  if (e < 32) {
#pragma unroll
    for (int r = 0; r < 4; ++r) {
      float h = rc1_b[e];
#pragma unroll 8
      for (int j = 0; j < 64; ++j) h += rc1_w[e * 64 + j] * smf[w][r][j];
      shid[w][r][e] = fmaxf(h, 0.f);
    }
  }
  __syncthreads();
  if (e < 16) {
    const int r = e >> 2, l = e & 3;
    float z = rc2_b[l];
#pragma unroll 8
    for (int j = 0; j < 32; ++j) z += rc2_w[l * 32 + j] * shid[w][r][j];
    float mx = z;
    mx = fmaxf(mx, __shfl_xor(mx, 1));
    mx = fmaxf(mx, __shfl_xor(mx, 2));
    const float ex = expf(z - mx);
    float s = ex;
    s += __shfl_xor(s, 1);
    s += __shfl_xor(s, 2);
    const float rp = ex / s;
    srp[w][r][l] = rp;
    mfrp[(size_t)(rowbase + r) * 68 + 64 + l] = rp;
  }
  __syncthreads();
  if (e < 4) {
    const int r = e;
    const float rp0 = srp[w][r][0], rp1 = srp[w][r][1], rp2 = srp[w][r][2], rp3 = srp[w][r][3];
    float z = ns2_b[0];
#pragma unroll
    for (int i = 0; i < 16; ++i) {
      float h = ns1_b[i] + ns1_w[i * 4 + 0] * rp0 + ns1_w[i * 4 + 1] * rp1 +
                ns1_w[i * 4 + 2] * rp2 + ns1_w[i * 4 + 3] * rp3;
      z += ns2_w[i] * fmaxf(h, 0.f);
    }
    nsc[rowbase + r] = 1.f / (1.f + expf(-z));
  }
}

// ---------- producers of the combined swizzled plane format ----------
// one thread = one logical 8-elem chunk; writes two 16B stores (limb0+limb1)
__device__ __forceinline__ void write_chunks(
    unsigned short* __restrict__ P, size_t row, int KT, int kt, int c,
    const float* vals8 /*8 floats*/) {
  unsigned short h0[8], h1[8];
#pragma unroll
  for (int s = 0; s < 8; ++s) split2(vals8[s], h0[s], h1[s]);
  const int r7 = (int)(row & 7);
  const size_t o = ((size_t)row * KT + kt) * 64;
  *(uint4*)&P[o + (size_t)((c ^ r7) * 8)] = *(const uint4*)h0;
  *(uint4*)&P[o + (size_t)(((4 + c) ^ r7) * 8)] = *(const uint4*)h1;
}

// gi = [x(512) | mfrp(580-512) | 0 pad] ; Kp=640, KT=20; items = rows*80
__global__ __launch_bounds__(256) void split_gi_v2(
    const float* __restrict__ x, const float* __restrict__ mfrp,
    unsigned short* __restrict__ P) {
  const unsigned idx = blockIdx.x * 256 + threadIdx.x;  // < 16384*80
  const unsigned row = idx / 80u;
  const unsigned item = idx - row * 80u;
  const int kt = item >> 2, c = item & 3;
  float v[8];
#pragma unroll
  for (int s = 0; s < 8; ++s) {
    const int k = kt * 32 + c * 8 + s;
    float f = 0.f;
    if (k < 512) f = x[(size_t)row * 512 + k];
    else if (k < 580) f = mfrp[(size_t)row * 68 + (k - 512)];
    v[s] = f;
  }
  write_chunks(P, row, 20, kt, c, v);
}

// weights: rows padded to Npad, cols padded to KT*32
__global__ __launch_bounds__(256) void split_w_v2(
    const float* __restrict__ W, unsigned short* __restrict__ P,
    int Nreal, int Kreal, int KT) {
  const unsigned idx = blockIdx.x * 256 + threadIdx.x;  // < Npad*KT*4
  const unsigned ipr = (unsigned)(KT * 4);
  const unsigned row = idx / ipr;
  const unsigned item = idx - row * ipr;
  const int kt = item >> 2, c = item & 3;
  float v[8];
#pragma unroll
  for (int s = 0; s < 8; ++s) {
    const int k = kt * 32 + c * 8 + s;
    v[s] = ((int)row < Nreal && k < Kreal) ? W[(size_t)row * Kreal + k] : 0.f;
  }
  write_chunks(P, row, KT, kt, c, v);
}

// ---------- 2) fp16x3 MFMA GEMM v3: conflict-free swizzled planes ----------
// C = A0B0 + 2^-11*(A1B0 + A0B1) + bias. Tile 128x128, BK=32, 4 waves.
// LDS [128][64] f16 (128B rows, 8 chunks); image IS the swizzled format.
__global__ __launch_bounds__(256, 2) void gemm_fp16x3_v3(
    const unsigned short* __restrict__ Ap, const unsigned short* __restrict__ Bp,
    const float* __restrict__ bias, float* __restrict__ C,
    int N, int KT, int ldc, int nbx) {
  __shared__ __align__(16) unsigned short As[2][128][64];
  __shared__ __align__(16) unsigned short Bs[2][128][64];
  const int t = threadIdx.x;
  // bijective XCD swizzle (gridDim.x % 8 == 0 for all launches)
  const int wg = (blockIdx.x & 7) * ((int)gridDim.x >> 3) + (blockIdx.x >> 3);
  const int bx = wg % nbx, by = wg / nbx;
  const int m0 = by * 128, n0 = bx * 128;
  const int w = t >> 6, l = t & 63;
  const int lr = l & 15, lc = l >> 4;
  const int wm = (w >> 1) * 64, wn = (w & 1) * 64;

  // staging: wave w covers rows w*32..w*32+31 in 4 calls of 8 rows x 128B
  const size_t stride = (size_t)KT * 64;
  size_t aoff[4], boff[4];
#pragma unroll
  for (int c = 0; c < 4; ++c) {
    const int rb = w * 32 + c * 8;
    aoff[c] = (size_t)(m0 + rb + (l >> 3)) * stride + (size_t)((l & 7) * 8);
    boff[c] = (size_t)(n0 + rb + (l >> 3)) * stride + (size_t)((l & 7) * 8);
  }

  f32x4 accM[4][4], accL[4][4];
#pragma unroll
  for (int i = 0; i < 4; ++i)
#pragma unroll
    for (int j = 0; j < 4; ++j) {
      accM[i][j] = (f32x4){0.f, 0.f, 0.f, 0.f};
      accL[i][j] = (f32x4){0.f, 0.f, 0.f, 0.f};
    }

  auto stage = [&](int kt, int bb) {
    const size_t ko = (size_t)kt * 64;
#pragma unroll
    for (int c = 0; c < 4; ++c) {
      const int rb = w * 32 + c * 8;
      gll16(Ap + aoff[c] + ko, &As[bb][rb][0]);
      gll16(Bp + boff[c] + ko, &Bs[bb][rb][0]);
    }
  };

  stage(0, 0);
  __syncthreads();
  int cur = 0;
  for (int kt = 0; kt < KT; ++kt) {
    if (kt + 1 < KT) stage(kt + 1, cur ^ 1);
    f16x8 a0[4], a1[4], b0[4], b1[4];
#pragma unroll
    for (int i = 0; i < 4; ++i) {
      const int ar = wm + i * 16 + lr;
      const int r7 = ar & 7;
      a0[i] = *(const f16x8*)&As[cur][ar][(lc ^ r7) * 8];
      a1[i] = *(const f16x8*)&As[cur][ar][((4 + lc) ^ r7) * 8];
    }
#pragma unroll
    for (int j = 0; j < 4; ++j) {
      const int brj = wn + j * 16 + lr;
      const int r7 = brj & 7;
      b0[j] = *(const f16x8*)&Bs[cur][brj][(lc ^ r7) * 8];
      b1[j] = *(const f16x8*)&Bs[cur][brj][((4 + lc) ^ r7) * 8];
    }
    // three passes of 16 independent MFMAs (no back-to-back same-acc deps)
#pragma unroll
    for (int i = 0; i < 4; ++i)
#pragma unroll
      for (int j = 0; j < 4; ++j)
        accM[i][j] = __builtin_amdgcn_mfma_f32_16x16x32_f16(a0[i], b0[j], accM[i][j], 0, 0, 0);
#pragma unroll
    for (int i = 0; i < 4; ++i)
#pragma unroll
      for (int j = 0; j < 4; ++j)
        accL[i][j] = __builtin_amdgcn_mfma_f32_16x16x32_f16(a1[i], b0[j], accL[i][j], 0, 0, 0);
#pragma unroll
    for (int i = 0; i < 4; ++i)
#pragma unroll
      for (int j = 0; j < 4; ++j)
        accL[i][j] = __builtin_amdgcn_mfma_f32_16x16x32_f16(a0[i], b1[j], accL[i][j], 0, 0, 0);
    __syncthreads();
    cur ^= 1;
  }
  // epilogue: D layout col(lane&15)=n, row((lane>>4)*4+reg)=m
#pragma unroll
  for (int j = 0; j < 4; ++j) {
    const int n = n0 + wn + j * 16 + lr;
    if (n < N) {
      const float bz = bias[n];
#pragma unroll
      for (int i = 0; i < 4; ++i) {
        const int mb = m0 + wm + i * 16 + lc * 4;
#pragma unroll
        for (int r = 0; r < 4; ++r)
          C[(size_t)(mb + r) * (size_t)ldc + n] =
              accM[i][j][r] + 0.00048828125f * accL[i][j][r] + bz;
      }
    }
  }
}

// ---------- 2b) G3: fp32 64x64-tile GEMM, grid 256 (full chip) ----------
__global__ __launch_bounds__(256, 4) void gemm64_kernel(
    const float* __restrict__ A, const float* __restrict__ W,
    const float* __restrict__ bias, float* __restrict__ C) {
  const int K = 580, N = 64;
  __shared__ float As[16][68];
  __shared__ float Bs[16][68];
  const int t = threadIdx.x;
  const int m0 = blockIdx.x * 64;
  const int tx = t & 15, ty = t >> 4;
  const int srow = t >> 2;
  const int skc = (t & 3) * 4;

  float acc[4][4] = {};
  for (int kt = 0; kt < 37; ++kt) {
    const int k = kt * 16 + skc;
    float4 va = {0.f, 0.f, 0.f, 0.f}, vb = {0.f, 0.f, 0.f, 0.f};
    if (k < K) {
      va = *(const float4*)(A + (size_t)(m0 + srow) * K + k);
      vb = *(const float4*)(W + (size_t)srow * K + k);
    }
    __syncthreads();
    As[skc + 0][srow] = va.x; As[skc + 1][srow] = va.y;
    As[skc + 2][srow] = va.z; As[skc + 3][srow] = va.w;
    Bs[skc + 0][srow] = vb.x; Bs[skc + 1][srow] = vb.y;
    Bs[skc + 2][srow] = vb.z; Bs[skc + 3][srow] = vb.w;
    __syncthreads();
#pragma unroll
    for (int kk = 0; kk < 16; ++kk) {
      const float4 a = *(const float4*)&As[kk][ty << 2];
      const float4 b = *(const float4*)&Bs[kk][tx << 2];
      const float aa[4] = {a.x, a.y, a.z, a.w};
      const float bb[4] = {b.x, b.y, b.z, b.w};
#pragma unroll
      for (int i = 0; i < 4; ++i)
#pragma unroll
        for (int j = 0; j < 4; ++j) acc[i][j] = fmaf(aa[i], bb[j], acc[i][j]);
    }
  }
  const float4 bz = *(const float4*)(bias + (tx << 2));
#pragma unroll
  for (int i = 0; i < 4; ++i) {
    const int m = m0 + (ty << 2) + i;
    float4 o;
    o.x = acc[i][0] + bz.x; o.y = acc[i][1] + bz.y;
    o.z = acc[i][2] + bz.z; o.w = acc[i][3] + bz.w;
    *(float4*)(C + (size_t)m * N + (tx << 2)) = o;
  }
}

// ---------- 3a) row LN + exact GELU -> swizzled plane format (z1) ----------
__global__ __launch_bounds__(256) void ln_gelu_split_v2(
    const float* __restrict__ Z, const float* __restrict__ gamma,
    const float* __restrict__ beta, unsigned short* __restrict__ P) {
  const int N = 1160, KT = 38;
  __shared__ float srow[1160];
  __shared__ float sred[4];
  const int t = threadIdx.x;
  const size_t row = blockIdx.x;
  const float* zr = Z + row * N;
  float vals[5];
  float s = 0.f;
#pragma unroll
  for (int c = 0; c < 5; ++c) {
    const int i = t + c * 256;
    float v = 0.f;
    if (i < N) { v = zr[i]; srow[i] = v; }
    vals[c] = v;
    s += v;
  }
  s = wsum64(s);
  if ((t & 63) == 0) sred[t >> 6] = s;
  __syncthreads();
  const float mu = (sred[0] + sred[1] + sred[2] + sred[3]) / (float)N;
  __syncthreads();
  float q = 0.f;
#pragma unroll
  for (int c = 0; c < 5; ++c) {
    const int i = t + c * 256;
    if (i < N) {
      const float d = vals[c] - mu;
      q += d * d;
    }
  }
  q = wsum64(q);
  if ((t & 63) == 0) sred[t >> 6] = q;
  __syncthreads();
  const float var = (sred[0] + sred[1] + sred[2] + sred[3]) / (float)N;
  const float rstd = 1.f / sqrtf(var + 1e-5f);
  // phase 2: 152 threads write 8-elem chunks in swizzled plane format
  if (t < KT * 4) {
    const int kt = t >> 2, c = t & 3;
    float v[8];
#pragma unroll
    for (int sdx = 0; sdx < 8; ++sdx) {
      const int k = kt * 32 + c * 8 + sdx;
      float g = 0.f;
      if (k < N) {
        const float y = (srow[k] - mu) * rstd * gamma[k] + beta[k];
        g = 0.5f * y * (1.f + erff(y * 0.70710678118654752f));
      }
      v[sdx] = g;
    }
    write_chunks(P, row, KT, kt, c, v);
  }
}

// ---------- 3b) in-place row LayerNorm + exact GELU (z2) ----------
__global__ __launch_bounds__(256) void ln_gelu_kernel(
    float* __restrict__ Z, const float* __restrict__ gamma,
    const float* __restrict__ beta, const int N) {
  __shared__ float sred[4];
  const int t = threadIdx.x;
  float* zr = Z + (size_t)blockIdx.x * N;
  float vals[5];
  float s = 0.f;
#pragma unroll
  for (int c = 0; c < 5; ++c) {
    const int i = t + c * 256;
    const float v = (i < N) ? zr[i] : 0.f;
    vals[c] = v;
    s += v;
  }
  s = wsum64(s);
  if ((t & 63) == 0) sred[t >> 6] = s;
  __syncthreads();
  const float mu = (sred[0] + sred[1] + sred[2] + sred[3]) / (float)N;
  __syncthreads();
  float q = 0.f;
#pragma unroll
  for (int c = 0; c < 5; ++c) {
    const int i = t + c * 256;
    if (i < N) {
      const float d = vals[c] - mu;
      q += d * d;
    }
  }
  q = wsum64(q);
  if ((t & 63) == 0) sred[t >> 6] = q;
  __syncthreads();
  const float var = (sred[0] + sred[1] + sred[2] + sred[3]) / (float)N;
  const float rstd = 1.f / sqrtf(var + 1e-5f);
#pragma unroll
  for (int c = 0; c < 5; ++c) {
    const int i = t + c * 256;
    if (i < N) {
      const float y = (vals[c] - mu) * rstd * gamma[i] + beta[i];
      zr[i] = 0.5f * y * (1.f + erff(y * 0.70710678118654752f));
    }
  }
}

// ---------- 4) final: +rp*spec^T, noise, top-2, gates, partials ----------
__global__ __launch_bounds__(256) void final_kernel(
    const float* __restrict__ clean, const float* __restrict__ mfrp,
    const float* __restrict__ nsc, const float* __restrict__ noise,
    const float* __restrict__ spec, float* __restrict__ out,
    float* __restrict__ pg, float* __restrict__ pl) {
  const int t = threadIdx.x;
  const int w = t >> 6;
  const int e = t & 63;
  __shared__ float sg[4][64];
  __shared__ float sl[4][64];
  const float4 sp = *(const float4*)(spec + e * 4);
  float accg = 0.f, accl = 0.f;
  for (int it = 0; it < 16; ++it) {
    const int row = blockIdx.x * 64 + it * 4 + w;
    const float4 rp = *(const float4*)(mfrp + (size_t)row * 68 + 64);
    float c = clean[(size_t)row * 64 + e];
    c += rp.x * sp.x + rp.y * sp.y + rp.z * sp.z + rp.w * sp.w;
    const float nv = noise[(size_t)row * 64 + e];
    const float noisy = c + nv * nsc[row];
    float v = noisy;
    int ix = e;
#pragma unroll
    for (int off = 32; off; off >>= 1) {
      const float ov = __shfl_xor(v, off);
      const int oi = __shfl_xor(ix, off);
      if (ov > v || (ov == v && oi < ix)) { v = ov; ix = oi; }
    }
    const float v1 = v;
    const int i1 = ix;
    float v2 = (e == i1) ? -FLT_MAX : noisy;
    int ix2 = e;
#pragma unroll
    for (int off = 32; off; off >>= 1) {
      const float ov = __shfl_xor(v2, off);
      const int oi = __shfl_xor(ix2, off);
      if (ov > v2 || (ov == v2 && oi < ix2)) { v2 = ov; ix2 = oi; }
    }
    const int i2 = ix2;
    if (e == 0) {
      const float texp = expf(v2 - v1);
      const float tw0 = 1.f / (1.f + texp);
      out[(size_t)row * 2 + 0] = tw0;
      out[(size_t)row * 2 + 1] = texp * tw0;
      out[32768 + (size_t)row * 2 + 0] = (float)i1;
      out[32768 + (size_t)row * 2 + 1] = (float)i2;
    }
    const float mx = wmax64(c);
    const float p = expf(c - mx);
    const float ssum = wsum64(p);
    accg += p / ssum;
    accl += (e == i1 || e == i2) ? 1.f : 0.f;
  }
  sg[w][e] = accg;
  sl[w][e] = accl;
  __syncthreads();
  if (t < 64) {
    pg[blockIdx.x * 64 + t] = sg[0][t] + sg[1][t] + sg[2][t] + sg[3][t];
    pl[blockIdx.x * 64 + t] = sl[0][t] + sl[1][t] + sl[2][t] + sl[3][t];
  }
}

// ---------- 5) aux loss ----------
__global__ void loss_kernel(const float* __restrict__ pg,
                            const float* __restrict__ pl,
                            float* __restrict__ out) {
  const int e = threadIdx.x;  // 64 threads
  float g = 0.f, l = 0.f;
  for (int b = 0; b < 256; ++b) {
    g += pg[b * 64 + e];
    l += pl[b * 64 + e];
  }
  const float prob = g * (1.f / 16384.f);
  const float ld = l * (1.f / 16384.f);
  const float load_loss = 64.f * wsum64(prob * ld);
  const float sgs = wsum64(g);
  const float mean = sgs * (1.f / 64.f);
  const float d = g - mean;
  const float var = wsum64(d * d) * (1.f / 63.f);
  if (e == 0) out[65536] = 0.01f * load_loss + 0.01f * (var / mean);
}

extern "C" void kernel_launch(void* const* d_in, const int* in_sizes, int n_in,
                              void* d_out, int out_size, void* d_ws, size_t ws_size,
                              hipStream_t stream) {
  (void)in_sizes; (void)n_in; (void)out_size; (void)ws_size;
  const float* x = (const float*)d_in[0];
  const float* noise = (const float*)d_in[1];
  const float* vol_w = (const float*)d_in[2];
  const float* vol_b = (const float*)d_in[3];
  const float* vol_g = (const float*)d_in[4];
  const float* vol_bb = (const float*)d_in[5];
  const float* trend_w = (const float*)d_in[6];
  const float* trend_b = (const float*)d_in[7];
  const float* trend_g = (const float*)d_in[8];
  const float* trend_bb = (const float*)d_in[9];
  const float* mom_w = (const float*)d_in[10];
  const float* mom_b = (const float*)d_in[11];
  const float* mom_g = (const float*)d_in[12];
  const float* mom_bb = (const float*)d_in[13];
  const float* reg_w = (const float*)d_in[14];
  const float* reg_b = (const float*)d_in[15];
  const float* reg_g = (const float*)d_in[16];
  const float* reg_bb = (const float*)d_in[17];
  const float* rc1_w = (const float*)d_in[18];
  const float* rc1_b = (const float*)d_in[19];
  const float* rc2_w = (const float*)d_in[20];
  const float* rc2_b = (const float*)d_in[21];
  const float* g1_w = (const float*)d_in[22];
  const float* g1_b = (const float*)d_in[23];
  const float* g1_g = (const float*)d_in[24];
  const float* g1_bb = (const float*)d_in[25];
  const float* g2_w = (const float*)d_in[26];
  const float* g2_b = (const float*)d_in[27];
  const float* g2_g = (const float*)d_in[28];
  const float* g2_bb = (const float*)d_in[29];
  const float* g3_w = (const float*)d_in[30];
  const float* g3_b = (const float*)d_in[31];
  const float* ns1_w = (const float*)d_in[32];
  const float* ns1_b = (const float*)d_in[33];
  const float* ns2_w = (const float*)d_in[34];
  const float* ns2_b = (const float*)d_in[35];
  const float* spec = (const float*)d_in[36];
  float* out = (float*)d_out;

  const size_t B = BROWS;
  float* ws = (float*)d_ws;
  float* mfrp = ws;                                   // B*68 f32
  float* nsc = mfrp + B * 68;                         // B f32
  float* z1 = nsc + B;                                // B*1160 f32
  unsigned short* gip = (unsigned short*)(z1 + B * 1160);  // B*1280 ush (KT=20)
  float* z2 = (float*)gip;                            // alias: B*580 f32 (fits)
  unsigned short* z1p = gip + B * 1280;               // B*2432 ush (KT=38)
  unsigned short* w1p = z1p + B * 2432;               // 1280*1280 ush
  unsigned short* w2p = w1p + (size_t)1280 * 1280;    // 640*2432 ush
  float* cln = (float*)(w2p + (size_t)640 * 2432);    // B*64 f32
  float* pg = cln + B * 64;                           // 256*64
  float* pl = pg + 256 * 64;                          // 256*64

  // weights -> swizzled planes (W1: Npad=1280,KT=20; W2: Npad=640,KT=38)
  split_w_v2<<<400, 256, 0, stream>>>(g1_w, w1p, 1160, 580, 20);
  split_w_v2<<<380, 256, 0, stream>>>(g2_w, w2p, 580, 1160, 38);

  encoder_kernel<<<1024, 256, 0, stream>>>(
      x, vol_w, vol_b, vol_g, vol_bb, trend_w, trend_b, trend_g, trend_bb,
      mom_w, mom_b, mom_g, mom_bb, reg_w, reg_b, reg_g, reg_bb,
      rc1_w, rc1_b, rc2_w, rc2_b, ns1_w, ns1_b, ns2_w, ns2_b, mfrp, nsc);

  split_gi_v2<<<5120, 256, 0, stream>>>(x, mfrp, gip);

  // G1: [16384,640] x [1280,640]^T -> z1 ; grid 1280 = 128 m-tiles x 10 n-tiles
  gemm_fp16x3_v3<<<1280, 256, 0, stream>>>(gip, w1p, g1_b, z1, 1160, 20, 1160, 10);
  ln_gelu_split_v2<<<BROWS, 256, 0, stream>>>(z1, g1_g, g1_bb, z1p);

  // G2: [16384,1216] x [640,1216]^T -> z2 ; grid 640 = 128 x 5
  gemm_fp16x3_v3<<<640, 256, 0, stream>>>(z1p, w2p, g2_b, z2, 580, 38, 580, 5);
  ln_gelu_kernel<<<BROWS, 256, 0, stream>>>(z2, g2_g, g2_bb, 580);

  // G3: [16384,580] x [64,580]^T -> clean (fp32, 256 blocks)
  gemm64_kernel<<<256, 256, 0, stream>>>(z2, g3_w, g3_b, cln);

  final_kernel<<<256, 256, 0, stream>>>(cln, mfrp, nsc, noise, spec, out, pg, pl);
  loss_kernel<<<1, 64, 0, stream>>>(pg, pl, out);
}